// Round 6
// baseline (4154.930 us; speedup 1.0000x reference)
//
#include <hip/hip_runtime.h>
#include <cstdint>
#include <cstddef>

// ---------------- config ----------------
#define BB 16
#define SS 512
#define DD 768
#define HH 12
#define FF 3072
#define LL 12
#define DHD 64
#define MM (BB*SS)   // 8192 rows

typedef __attribute__((ext_vector_type(8))) short bf16x8;
typedef __attribute__((ext_vector_type(4))) float f32x4;

__device__ __forceinline__ ushort f2bf(float f) {
  union { float f; uint32_t u; } x; x.f = f;
  uint32_t r = x.u + 0x7FFFu + ((x.u >> 16) & 1u);
  return (ushort)(r >> 16);
}

__device__ __forceinline__ void glds16(const ushort* g, ushort* l) {
  __builtin_amdgcn_global_load_lds((__attribute__((address_space(1))) void*)g,
                                   (__attribute__((address_space(3))) void*)l,
                                   16, 0, 0);
}

__device__ __forceinline__ float gelu_t(float v) {
  // tanh-form gelu; |err| vs exact erf-gelu < ~3e-4, below bf16 ulp here
  float y = 0.7978845608f * (v + 0.044715f * v * v * v);
  y = fminf(fmaxf(y, -15.f), 15.f);
  float e = __expf(2.f * y);
  return 0.5f * v * (2.f - 2.f / (e + 1.f));
}

// ================= weight f32 -> bf16 conversion (up to 4 tensors) =================
__global__ __launch_bounds__(256)
void convw4(const float* __restrict__ s0, const float* __restrict__ s1,
            const float* __restrict__ s2, const float* __restrict__ s3,
            ushort* __restrict__ dst, int per)
{
  const float* s = blockIdx.y == 0 ? s0 : blockIdx.y == 1 ? s1 : blockIdx.y == 2 ? s2 : s3;
  const int i = (blockIdx.x * 256 + threadIdx.x) * 4;
  if (i >= per) return;
  const float4 v = *(const float4*)(s + i);
  ushort4 o;
  o.x = f2bf(v.x); o.y = f2bf(v.y); o.z = f2bf(v.z); o.w = f2bf(v.w);
  *(ushort4*)(dst + (size_t)blockIdx.y * per + i) = o;
}

// ================= embedding + LayerNorm =================
__global__ __launch_bounds__(256)
void embed_ln_kernel(const int* __restrict__ ids, const float* __restrict__ wemb,
                     const float* __restrict__ pemb, const float* __restrict__ g,
                     const float* __restrict__ bt, float* __restrict__ hf,
                     ushort* __restrict__ hb)
{
  const int row = blockIdx.x;
  const int s = row & (SS - 1);
  const int id = ids[row];
  const float* wp = wemb + (size_t)id * DD;
  const float* pp = pemb + (size_t)s * DD;
  const int tid = threadIdx.x;
  float v[3]; float sum = 0.f, sq = 0.f;
#pragma unroll
  for (int j = 0; j < 3; ++j) {
    int e = tid + j * 256;
    v[j] = wp[e] + pp[e];
    sum += v[j]; sq += v[j] * v[j];
  }
  __shared__ float red[2][4];
#pragma unroll
  for (int off = 32; off >= 1; off >>= 1) { sum += __shfl_xor(sum, off); sq += __shfl_xor(sq, off); }
  const int lane = tid & 63, wid = tid >> 6;
  if (lane == 0) { red[0][wid] = sum; red[1][wid] = sq; }
  __syncthreads();
  sum = red[0][0] + red[0][1] + red[0][2] + red[0][3];
  sq  = red[1][0] + red[1][1] + red[1][2] + red[1][3];
  const float mean = sum * (1.f / DD);
  const float var  = sq  * (1.f / DD) - mean * mean;
  const float rstd = rsqrtf(var + 1e-12f);
  const size_t base = (size_t)row * DD;
#pragma unroll
  for (int j = 0; j < 3; ++j) {
    int e = tid + j * 256;
    float o = (v[j] - mean) * rstd * g[e] + bt[e];
    hf[base + e] = o;
    hb[base + e] = f2bf(o);
  }
}

// ================= residual add + LayerNorm =================
__global__ __launch_bounds__(256)
void add_ln_kernel(const float* __restrict__ res, const float* __restrict__ add,
                   const float* __restrict__ g, const float* __restrict__ bt,
                   float* __restrict__ hf, ushort* __restrict__ hb)
{
  const int row = blockIdx.x;
  const int tid = threadIdx.x;
  const size_t base = (size_t)row * DD;
  float v[3]; float sum = 0.f, sq = 0.f;
#pragma unroll
  for (int j = 0; j < 3; ++j) {
    int e = tid + j * 256;
    v[j] = res[base + e] + add[base + e];
    sum += v[j]; sq += v[j] * v[j];
  }
  __shared__ float red[2][4];
#pragma unroll
  for (int off = 32; off >= 1; off >>= 1) { sum += __shfl_xor(sum, off); sq += __shfl_xor(sq, off); }
  const int lane = tid & 63, wid = tid >> 6;
  if (lane == 0) { red[0][wid] = sum; red[1][wid] = sq; }
  __syncthreads();
  sum = red[0][0] + red[0][1] + red[0][2] + red[0][3];
  sq  = red[1][0] + red[1][1] + red[1][2] + red[1][3];
  const float mean = sum * (1.f / DD);
  const float var  = sq  * (1.f / DD) - mean * mean;
  const float rstd = rsqrtf(var + 1e-12f);
#pragma unroll
  for (int j = 0; j < 3; ++j) {
    int e = tid + j * 256;
    float o = (v[j] - mean) * rstd * g[e] + bt[e];
    hf[base + e] = o;
    hb[base + e] = f2bf(o);
  }
}

// ================= 8-phase 256x256 GEMM, K=768 (NT=12 K-tiles of 64) =================
// C[M,N] = A[M,768](bf16) @ Bw[N,768](bf16)^T + bias
// MODE 0: QKV fused (N=2304; sub=bn/3: Q,K row-major bf16; V transposed vT[b][h][d][s])
// MODE 1: FFN1 (N=3072; gelu, bf16 out)
// Schedule: per K-tile 4 phases (kk=q>>1 k-half, mh=q&1 M-half); 1 stage-unit
// ([256][32] = 16KB) per phase; counted vmcnt(4) once per tile (never 0 until tail);
// raw s_barrier (no compiler vmcnt-drain); setprio around MFMA cluster.
template<int MODE>
__global__ __launch_bounds__(512, 2)
void gemm8(const ushort* __restrict__ A, const ushort* __restrict__ Bw,
           const float* __restrict__ b0, const float* __restrict__ b1,
           const float* __restrict__ b2,
           ushort* __restrict__ o0, ushort* __restrict__ o1, ushort* __restrict__ o2)
{
  // [slot][khalf][row][kslot*8] ; each [256][32] unit is 16KB contiguous (glds linear dest)
  __shared__ ushort Asl[2][2][256][32];
  __shared__ ushort Bsl[2][2][256][32];

  const int tid = threadIdx.x;
  const int lane = tid & 63, wv = tid >> 6;
  const int wr = wv >> 2, wc = wv & 3;          // 2 M-waves x 4 N-waves
  const int fr = lane & 15, fg = lane >> 4;

  // bijective XCD swizzle (grid counts divisible by 8)
  int id = blockIdx.y * gridDim.x + blockIdx.x;
  const int chunk = (gridDim.x * gridDim.y) >> 3;
  id = (id & 7) * chunk + (id >> 3);
  const int bm = id & 31;                       // gridDim.x == 32
  const int bn = id >> 5;

  // staging lambdas: one unit = [256 rows][32 k] of one tensor at (kt, khalf)
  auto stA = [&](int kt, int kh) {
#pragma unroll
    for (int j = 0; j < 2; ++j) {
      const int slot = j * 512 + tid;
      const int row = slot >> 2;
      const int gks = (slot & 3) ^ ((row >> 1) & 3);   // inverse swizzle on global src
      const ushort* g = A + (size_t)(bm * 256 + row) * 768 + kt * 64 + kh * 32 + gks * 8;
      glds16(g, &Asl[kt & 1][kh][0][0] + (j * 512 + wv * 64) * 8);
    }
  };
  auto stB = [&](int kt, int kh) {
#pragma unroll
    for (int j = 0; j < 2; ++j) {
      const int slot = j * 512 + tid;
      const int row = slot >> 2;
      const int gks = (slot & 3) ^ ((row >> 1) & 3);
      const ushort* g = Bw + (size_t)(bn * 256 + row) * 768 + kt * 64 + kh * 32 + gks * 8;
      glds16(g, &Bsl[kt & 1][kh][0][0] + (j * 512 + wv * 64) * 8);
    }
  };

  f32x4 acc[8][4];
#pragma unroll
  for (int i = 0; i < 8; ++i)
#pragma unroll
    for (int j = 0; j < 4; ++j) acc[i][j] = f32x4{0.f, 0.f, 0.f, 0.f};

  // prologue: tile0 complete + tile1 kh0 (6 units, 12 loads); leave last 2 units in flight
  stA(0, 0); stB(0, 0); stA(0, 1); stB(0, 1); stA(1, 0); stB(1, 0);
  asm volatile("s_waitcnt vmcnt(4)" ::: "memory");
  asm volatile("s_barrier" ::: "memory");

  const int NT = 12;
  for (int kt = 0; kt < NT; ++kt) {
    const int slot = kt & 1;
#pragma unroll
    for (int q = 0; q < 4; ++q) {
      const int kk = q >> 1, mh = q & 1;
      // ds-load register subtiles (8 x ds_read_b128, swizzled)
      bf16x8 bf[4], af[4];
#pragma unroll
      for (int j = 0; j < 4; ++j) {
        const int row = wc * 64 + j * 16 + fr;
        bf[j] = *(const bf16x8*)&Bsl[slot][kk][row][(fg ^ ((row >> 1) & 3)) * 8];
      }
#pragma unroll
      for (int i = 0; i < 4; ++i) {
        const int row = wr * 128 + mh * 64 + i * 16 + fr;
        af[i] = *(const bf16x8*)&Asl[slot][kk][row][(fg ^ ((row >> 1) & 3)) * 8];
      }
      // stage one unit (region free: last read 2 phases ago)
      if (q == 0)      { if (kt + 1 < NT) stA(kt + 1, 1); }
      else if (q == 1) { if (kt + 1 < NT) stB(kt + 1, 1); }
      else if (q == 2) { if (kt + 2 < NT) stA(kt + 2, 0); }
      else             { if (kt + 2 < NT) stB(kt + 2, 0); }
      // counted wait once per tile, gating next tile's reads
      if (q == 3) {
        if (kt < NT - 2)       { asm volatile("s_waitcnt vmcnt(4)" ::: "memory"); }
        else if (kt == NT - 2) { asm volatile("s_waitcnt vmcnt(0)" ::: "memory"); }
      }
      asm volatile("s_barrier" ::: "memory");
      asm volatile("s_waitcnt lgkmcnt(0)" ::: "memory");
      __builtin_amdgcn_s_setprio(1);
#pragma unroll
      for (int i = 0; i < 4; ++i)
#pragma unroll
        for (int j = 0; j < 4; ++j)
          acc[mh * 4 + i][j] =
            __builtin_amdgcn_mfma_f32_16x16x32_bf16(bf[j], af[i], acc[mh * 4 + i][j], 0, 0, 0);
      __builtin_amdgcn_s_setprio(0);
      asm volatile("s_barrier" ::: "memory");
    }
  }

  // epilogue — swapped-operand layout: lane holds row m = ...+fr, cols n = ...+fg*4+r
  if (MODE == 0) {
    const int sub = bn / 3;                          // 0=Q 1=K 2=V
    const int cb = (bn - sub * 3) * 256 + wc * 64;   // col base within 768
    const float* bias = sub == 0 ? b0 : (sub == 1 ? b1 : b2);
    ushort* out = sub == 0 ? o0 : o1;
#pragma unroll
    for (int ig = 0; ig < 8; ++ig) {
      const int row_g = bm * 256 + wr * 128 + ig * 16 + fr;
#pragma unroll
      for (int j = 0; j < 4; ++j) {
        const int col = cb + j * 16 + fg * 4;
        const float4 bv4 = *(const float4*)&bias[col];
        const float v0 = acc[ig][j][0] + bv4.x;
        const float v1 = acc[ig][j][1] + bv4.y;
        const float v2 = acc[ig][j][2] + bv4.z;
        const float v3 = acc[ig][j][3] + bv4.w;
        if (sub < 2) {
          ushort4 o4; o4.x = f2bf(v0); o4.y = f2bf(v1); o4.z = f2bf(v2); o4.w = f2bf(v3);
          *(ushort4*)&out[(size_t)row_g * DD + col] = o4;
        } else {
          // V transposed: vT[((b*H + h)*DH + d)*S + s]
          const int b_ = row_g >> 9, s_ = row_g & 511;
          const int h_ = col >> 6, d0 = col & 63;
          ushort* vp = o2 + (((size_t)(b_ * HH + h_) * DHD + d0) * SS + s_);
          vp[0] = f2bf(v0); vp[SS] = f2bf(v1); vp[2 * SS] = f2bf(v2); vp[3 * SS] = f2bf(v3);
        }
      }
    }
  } else {
#pragma unroll
    for (int ig = 0; ig < 8; ++ig) {
      const int row_g = bm * 256 + wr * 128 + ig * 16 + fr;
#pragma unroll
      for (int j = 0; j < 4; ++j) {
        const int col = bn * 256 + wc * 64 + j * 16 + fg * 4;
        const float4 bv4 = *(const float4*)&b0[col];
        ushort4 o4;
        o4.x = f2bf(gelu_t(acc[ig][j][0] + bv4.x));
        o4.y = f2bf(gelu_t(acc[ig][j][1] + bv4.y));
        o4.z = f2bf(gelu_t(acc[ig][j][2] + bv4.z));
        o4.w = f2bf(gelu_t(acc[ig][j][3] + bv4.w));
        *(ushort4*)&o0[(size_t)row_g * FF + col] = o4;
      }
    }
  }
}

// ================= 2-phase 128x128 GEMM (O-proj, Wd: N=768) =================
// EPI 1: f32 out + bias
template<int EPI>
__global__ __launch_bounds__(256, 2)
void gemm_ker(const ushort* __restrict__ A, const ushort* __restrict__ Bw,
              const float* __restrict__ bias, void* __restrict__ Cout,
              int Ndim, int Kdim)
{
  __shared__ ushort As[2][128 * 32];
  __shared__ ushort Bs[2][128 * 32];

  int id = blockIdx.y * gridDim.x + blockIdx.x;
  const int chunk = (gridDim.x * gridDim.y) >> 3;
  id = (id & 7) * chunk + (id >> 3);
  const int bm = id & 63;
  const int bn = id >> 6;

  const int tid = threadIdx.x;
  const int l = tid & 63, w = tid >> 6;
  const int wm = w >> 1, wn = w & 1;
  const int fr = l & 15, fg = l >> 4;

  const int srow = l >> 2;
  const int scol = (l & 3) * 8;
  const ushort* Agl = A  + (size_t)(bm * 128 + w * 32 + srow) * Kdim + scol;
  const ushort* Bgl = Bw + (size_t)(bn * 128 + w * 32 + srow) * Kdim + scol;
  ushort* AsW = &As[0][(w * 32) * 32];
  ushort* BsW = &Bs[0][(w * 32) * 32];

  auto stage = [&](int buf, int kt) {
    const ushort* a = Agl + kt * 32;
    const ushort* b = Bgl + kt * 32;
    ushort* al = AsW + buf * 4096;
    ushort* bl = BsW + buf * 4096;
    glds16(a,                     al);
    glds16(a + 16 * (size_t)Kdim, al + 512);
    glds16(b,                     bl);
    glds16(b + 16 * (size_t)Kdim, bl + 512);
  };

  f32x4 acc[4][4];
#pragma unroll
  for (int i = 0; i < 4; ++i)
#pragma unroll
    for (int j = 0; j < 4; ++j) acc[i][j] = f32x4{0.f, 0.f, 0.f, 0.f};

  stage(0, 0);
  __syncthreads();
  const int nk = Kdim >> 5;
  int cur = 0;
  for (int kt = 0; kt < nk; ++kt) {
    if (kt + 1 < nk) stage(cur ^ 1, kt + 1);
    bf16x8 af[4], bfv[4];
#pragma unroll
    for (int i = 0; i < 4; ++i) af[i]  = *(const bf16x8*)&As[cur][(wm * 64 + i * 16 + fr) * 32 + fg * 8];
#pragma unroll
    for (int j = 0; j < 4; ++j) bfv[j] = *(const bf16x8*)&Bs[cur][(wn * 64 + j * 16 + fr) * 32 + fg * 8];
#pragma unroll
    for (int i = 0; i < 4; ++i)
#pragma unroll
      for (int j = 0; j < 4; ++j)
        acc[i][j] = __builtin_amdgcn_mfma_f32_16x16x32_bf16(af[i], bfv[j], acc[i][j], 0, 0, 0);
    __syncthreads();
    cur ^= 1;
  }

#pragma unroll
  for (int i = 0; i < 4; ++i) {
    const int row0 = bm * 128 + wm * 64 + i * 16 + fg * 4;
#pragma unroll
    for (int j = 0; j < 4; ++j) {
      const int col = bn * 128 + wn * 64 + j * 16 + fr;
      const float bv = bias[col];
#pragma unroll
      for (int r = 0; r < 4; ++r) {
        float v = acc[i][j][r] + bv;
        if (EPI == 1) ((float*)Cout)[(size_t)(row0 + r) * Ndim + col] = v;
        else          ((ushort*)Cout)[(size_t)(row0 + r) * Ndim + col] = f2bf(v);
      }
    }
  }
}

// ================= fused flash attention (V pre-transposed) =================
__global__ __launch_bounds__(256, 2)
void attn_kernel(const ushort* __restrict__ qb, const ushort* __restrict__ kb,
                 const ushort* __restrict__ vt, const float* __restrict__ relt,
                 const float* __restrict__ amask, ushort* __restrict__ ctxb)
{
  __shared__ ushort Kt[128][72];
  __shared__ ushort Vt[64][136];
  __shared__ ushort Pl[64][136];
  __shared__ float am_lds[512];
  __shared__ float rel_lds[1024];

  const int tid = threadIdx.x, lane = tid & 63, w = tid >> 6;

  int lin = blockIdx.y * gridDim.x + blockIdx.x;
  lin = (lin & 7) * 192 + (lin >> 3);
  const int qt = lin & 7;
  const int bh = lin >> 3;
  const int b = bh / HH, h = bh - b * HH;
  const int fr = lane & 15, fg = lane >> 4;

  for (int i = tid; i < 512; i += 256)
    am_lds[i] = (1.0f - amask[b * SS + i]) * -10000.0f;
  for (int i = tid; i < 1024; i += 256) {
    int d = i - 512;
    d = min(128, max(-128, d));
    rel_lds[i] = relt[(d + 128) * HH + h];
  }

  bf16x8 qf[2];
  {
    const int qrow = qt * 64 + w * 16 + fr;
    const ushort* p = qb + ((size_t)(b * SS + qrow) * DD) + h * DHD + fg * 8;
    qf[0] = *(const bf16x8*)p;
    qf[1] = *(const bf16x8*)(p + 32);
  }

  f32x4 o[4];
  float mrow[4], lrow[4];
#pragma unroll
  for (int r = 0; r < 4; ++r) { mrow[r] = -1e30f; lrow[r] = 0.f; }
#pragma unroll
  for (int d = 0; d < 4; ++d) o[d] = f32x4{0.f, 0.f, 0.f, 0.f};

  const int skr = tid >> 1;
  const int shd = (tid & 1) * 32;
  const int vrow = tid >> 2;
  const int vcg  = (tid & 3) * 32;
  const ushort* vgl = vt + ((size_t)bh * DHD + vrow) * SS + vcg;

  const int qg0 = qt * 64 + w * 16;

  for (int kt = 0; kt < 4; ++kt) {
    const size_t gbase = ((size_t)(b * SS + kt * 128 + skr) * DD) + h * DHD + shd;
    int4 kr0 = *(const int4*)(kb + gbase);
    int4 kr1 = *(const int4*)(kb + gbase + 8);
    int4 kr2 = *(const int4*)(kb + gbase + 16);
    int4 kr3 = *(const int4*)(kb + gbase + 24);
    const ushort* vp = vgl + kt * 128;
    int4 vr0 = *(const int4*)(vp);
    int4 vr1 = *(const int4*)(vp + 8);
    int4 vr2 = *(const int4*)(vp + 16);
    int4 vr3 = *(const int4*)(vp + 24);

    __syncthreads();
    *(int4*)&Kt[skr][shd]      = kr0;
    *(int4*)&Kt[skr][shd + 8]  = kr1;
    *(int4*)&Kt[skr][shd + 16] = kr2;
    *(int4*)&Kt[skr][shd + 24] = kr3;
    *(int4*)&Vt[vrow][vcg]      = vr0;
    *(int4*)&Vt[vrow][vcg + 8]  = vr1;
    *(int4*)&Vt[vrow][vcg + 16] = vr2;
    *(int4*)&Vt[vrow][vcg + 24] = vr3;
    __syncthreads();

    float sv[8][4];
    __builtin_amdgcn_s_setprio(1);
#pragma unroll
    for (int kc = 0; kc < 8; ++kc) {
      f32x4 s = f32x4{0.f, 0.f, 0.f, 0.f};
      bf16x8 kf0 = *(const bf16x8*)&Kt[kc * 16 + fr][fg * 8];
      bf16x8 kf1 = *(const bf16x8*)&Kt[kc * 16 + fr][32 + fg * 8];
      s = __builtin_amdgcn_mfma_f32_16x16x32_bf16(qf[0], kf0, s, 0, 0, 0);
      s = __builtin_amdgcn_mfma_f32_16x16x32_bf16(qf[1], kf1, s, 0, 0, 0);
      const int col = kt * 128 + kc * 16 + fr;
      const float am = am_lds[col];
      const int ridx = col - qg0 - fg * 4 + 512;
#pragma unroll
      for (int r = 0; r < 4; ++r)
        sv[kc][r] = s[r] * 0.125f + rel_lds[ridx - r] + am;
    }
    __builtin_amdgcn_s_setprio(0);

    float ef[4];
#pragma unroll
    for (int r = 0; r < 4; ++r) {
      float tmax = sv[0][r];
#pragma unroll
      for (int kc = 1; kc < 8; ++kc) tmax = fmaxf(tmax, sv[kc][r]);
#pragma unroll
      for (int off = 1; off < 16; off <<= 1) tmax = fmaxf(tmax, __shfl_xor(tmax, off));
      const float mnew = fmaxf(mrow[r], tmax);
      ef[r] = __expf(mrow[r] - mnew);
      float psum = 0.f;
      const int prow = w * 16 + fg * 4 + r;
#pragma unroll
      for (int kc = 0; kc < 8; ++kc) {
        float p = __expf(sv[kc][r] - mnew);
        psum += p;
        Pl[prow][kc * 16 + fr] = f2bf(p);
      }
#pragma unroll
      for (int off = 1; off < 16; off <<= 1) psum += __shfl_xor(psum, off);
      lrow[r] = lrow[r] * ef[r] + psum;
      mrow[r] = mnew;
    }
#pragma unroll
    for (int dc = 0; dc < 4; ++dc)
#pragma unroll
      for (int r = 0; r < 4; ++r) o[dc][r] *= ef[r];
    __syncthreads();

    __builtin_amdgcn_s_setprio(1);
#pragma unroll
    for (int dc = 0; dc < 4; ++dc)
#pragma unroll
      for (int ks = 0; ks < 4; ++ks) {
        bf16x8 pf = *(const bf16x8*)&Pl[w * 16 + fr][ks * 32 + fg * 8];
        bf16x8 vf = *(const bf16x8*)&Vt[dc * 16 + fr][ks * 32 + fg * 8];
        o[dc] = __builtin_amdgcn_mfma_f32_16x16x32_bf16(pf, vf, o[dc], 0, 0, 0);
      }
    __builtin_amdgcn_s_setprio(0);
  }

#pragma unroll
  for (int dc = 0; dc < 4; ++dc)
#pragma unroll
    for (int r = 0; r < 4; ++r) {
      const int qg = qt * 64 + w * 16 + fg * 4 + r;
      const float v = o[dc][r] / lrow[r];
      ctxb[((size_t)(b * SS + qg) * DD) + h * DHD + dc * 16 + fr] = f2bf(v);
    }
}

// ================= host launch =================
extern "C" void kernel_launch(void* const* d_in, const int* in_sizes, int n_in,
                              void* d_out, int out_size, void* d_ws, size_t ws_size,
                              hipStream_t stream) {
  const int*   ids   = (const int*)d_in[0];
  const float* amask = (const float*)d_in[1];
  const float* wemb  = (const float*)d_in[2];
  const float* pemb  = (const float*)d_in[3];
  const float* eln_w = (const float*)d_in[4];
  const float* eln_b = (const float*)d_in[5];
  const float* relt  = (const float*)d_in[6];
  const float* Wq    = (const float*)d_in[7];
  const float* bq    = (const float*)d_in[8];
  const float* Wk    = (const float*)d_in[9];
  const float* bk    = (const float*)d_in[10];
  const float* Wv    = (const float*)d_in[11];
  const float* bv    = (const float*)d_in[12];
  const float* Wo    = (const float*)d_in[13];
  const float* bo    = (const float*)d_in[14];
  const float* aln_w = (const float*)d_in[15];
  const float* aln_b = (const float*)d_in[16];
  const float* Wi    = (const float*)d_in[17];
  const float* bi    = (const float*)d_in[18];
  const float* Wd    = (const float*)d_in[19];
  const float* bd    = (const float*)d_in[20];
  const float* oln_w = (const float*)d_in[21];
  const float* oln_b = (const float*)d_in[22];

  size_t off = 0;
  auto carve = [&](size_t bytes) -> void* {
    void* r = (char*)d_ws + off;
    off += (bytes + 255) & ~(size_t)255;
    return r;
  };
  float*  hf     = (float*) carve((size_t)MM * DD * 4);
  ushort* hb     = (ushort*)carve((size_t)MM * DD * 2);
  ushort* qbuf   = (ushort*)carve((size_t)MM * DD * 2);
  ushort* kbuf   = (ushort*)carve((size_t)MM * DD * 2);
  ushort* vbuf   = (ushort*)carve((size_t)MM * DD * 2);   // vT[b][h][d][s]
  ushort* ctxb   = (ushort*)carve((size_t)MM * DD * 2);
  float*  gout   = (float*) carve((size_t)MM * DD * 4);
  ushort* interb = (ushort*)carve((size_t)MM * FF * 2);

  ushort* wA = interb;   // Wq,Wk,Wv,Wo bf16 in interb's dead window
  ushort* wB = qbuf;     // Wi,Wd bf16 in qbuf's dead window (after attn)
  const int PD = DD * DD;
  const int PF = FF * DD;

  embed_ln_kernel<<<MM, 256, 0, stream>>>(ids, wemb, pemb, eln_w, eln_b, hf, hb);

  const dim3 gQKV(MM / 256, 9);               // 32 x 9 (N=2304)
  const dim3 gF1(MM / 256, FF / 256);         // 32 x 12
  const dim3 gD(MM / 128, DD / 128);          // 64 x 6
  const dim3 gA(SS / 64, BB * HH);            // 8 x 192
  const dim3 gCA(PD / 1024, 4);
  const dim3 gCB(PF / 1024, 2);

  for (int l = 0; l < LL; ++l) {
    const size_t wo  = (size_t)l * PD;
    const size_t wio = (size_t)l * PF;

    convw4<<<gCA, 256, 0, stream>>>(Wq + wo, Wk + wo, Wv + wo, Wo + wo, wA, PD);

    gemm8<0><<<gQKV, 512, 0, stream>>>(hb, wA, bq + l * DD, bk + l * DD, bv + l * DD,
                                       qbuf, kbuf, vbuf);

    attn_kernel<<<gA, 256, 0, stream>>>(qbuf, kbuf, vbuf, relt, amask, ctxb);

    convw4<<<gCB, 256, 0, stream>>>(Wi + wio, Wd + wio, Wi + wio, Wi + wio, wB, PF);

    gemm_ker<1><<<gD, 256, 0, stream>>>(ctxb, wA + 3 * PD, bo + l * DD, gout, DD, DD);
    add_ln_kernel<<<MM, 256, 0, stream>>>(hf, gout, aln_w + l * DD, aln_b + l * DD, hf, hb);

    gemm8<1><<<gF1, 512, 0, stream>>>(hb, wB, bi + l * FF, nullptr, nullptr,
                                      interb, nullptr, nullptr);
    gemm_ker<1><<<gD, 256, 0, stream>>>(interb, wB + PF, bd + l * DD, gout, DD, FF);

    float* outp = (l == LL - 1) ? (float*)d_out : hf;
    add_ln_kernel<<<MM, 256, 0, stream>>>(hf, gout, oln_w + l * DD, oln_b + l * DD, outp, hb);
  }
}

// Round 7
// 4154.915 us; speedup vs baseline: 1.0000x; 1.0000x over previous
//
#include <hip/hip_runtime.h>
#include <cstdint>
#include <cstddef>

// ---------------- config ----------------
#define BB 16
#define SS 512
#define DD 768
#define HH 12
#define FF 3072
#define LL 12
#define DHD 64
#define MM (BB*SS)   // 8192 rows

typedef __attribute__((ext_vector_type(8))) short bf16x8;
typedef __attribute__((ext_vector_type(4))) float f32x4;

__device__ __forceinline__ ushort f2bf(float f) {
  union { float f; uint32_t u; } x; x.f = f;
  uint32_t r = x.u + 0x7FFFu + ((x.u >> 16) & 1u);
  return (ushort)(r >> 16);
}

__device__ __forceinline__ void glds16(const ushort* g, ushort* l) {
  __builtin_amdgcn_global_load_lds((__attribute__((address_space(1))) void*)g,
                                   (__attribute__((address_space(3))) void*)l,
                                   16, 0, 0);
}

__device__ __forceinline__ float gelu_t(float v) {
  // tanh-form gelu; |err| vs exact erf-gelu < ~3e-4, below bf16 ulp here
  float y = 0.7978845608f * (v + 0.044715f * v * v * v);
  y = fminf(fmaxf(y, -15.f), 15.f);
  float e = __expf(2.f * y);
  return 0.5f * v * (2.f - 2.f / (e + 1.f));
}

// ================= weight f32 -> bf16 conversion (up to 4 tensors) =================
__global__ __launch_bounds__(256)
void convw4(const float* __restrict__ s0, const float* __restrict__ s1,
            const float* __restrict__ s2, const float* __restrict__ s3,
            ushort* __restrict__ dst, int per)
{
  const float* s = blockIdx.y == 0 ? s0 : blockIdx.y == 1 ? s1 : blockIdx.y == 2 ? s2 : s3;
  const int i = (blockIdx.x * 256 + threadIdx.x) * 4;
  if (i >= per) return;
  const float4 v = *(const float4*)(s + i);
  ushort4 o;
  o.x = f2bf(v.x); o.y = f2bf(v.y); o.z = f2bf(v.z); o.w = f2bf(v.w);
  *(ushort4*)(dst + (size_t)blockIdx.y * per + i) = o;
}

// ================= embedding + LayerNorm =================
__global__ __launch_bounds__(256)
void embed_ln_kernel(const int* __restrict__ ids, const float* __restrict__ wemb,
                     const float* __restrict__ pemb, const float* __restrict__ g,
                     const float* __restrict__ bt, float* __restrict__ hf,
                     ushort* __restrict__ hb)
{
  const int row = blockIdx.x;
  const int s = row & (SS - 1);
  const int id = ids[row];
  const float* wp = wemb + (size_t)id * DD;
  const float* pp = pemb + (size_t)s * DD;
  const int tid = threadIdx.x;
  float v[3]; float sum = 0.f, sq = 0.f;
#pragma unroll
  for (int j = 0; j < 3; ++j) {
    int e = tid + j * 256;
    v[j] = wp[e] + pp[e];
    sum += v[j]; sq += v[j] * v[j];
  }
  __shared__ float red[2][4];
#pragma unroll
  for (int off = 32; off >= 1; off >>= 1) { sum += __shfl_xor(sum, off); sq += __shfl_xor(sq, off); }
  const int lane = tid & 63, wid = tid >> 6;
  if (lane == 0) { red[0][wid] = sum; red[1][wid] = sq; }
  __syncthreads();
  sum = red[0][0] + red[0][1] + red[0][2] + red[0][3];
  sq  = red[1][0] + red[1][1] + red[1][2] + red[1][3];
  const float mean = sum * (1.f / DD);
  const float var  = sq  * (1.f / DD) - mean * mean;
  const float rstd = rsqrtf(var + 1e-12f);
  const size_t base = (size_t)row * DD;
#pragma unroll
  for (int j = 0; j < 3; ++j) {
    int e = tid + j * 256;
    float o = (v[j] - mean) * rstd * g[e] + bt[e];
    hf[base + e] = o;
    hb[base + e] = f2bf(o);
  }
}

// ================= residual add + LayerNorm =================
__global__ __launch_bounds__(256)
void add_ln_kernel(const float* __restrict__ res, const float* __restrict__ add,
                   const float* __restrict__ g, const float* __restrict__ bt,
                   float* __restrict__ hf, ushort* __restrict__ hb)
{
  const int row = blockIdx.x;
  const int tid = threadIdx.x;
  const size_t base = (size_t)row * DD;
  float v[3]; float sum = 0.f, sq = 0.f;
#pragma unroll
  for (int j = 0; j < 3; ++j) {
    int e = tid + j * 256;
    v[j] = res[base + e] + add[base + e];
    sum += v[j]; sq += v[j] * v[j];
  }
  __shared__ float red[2][4];
#pragma unroll
  for (int off = 32; off >= 1; off >>= 1) { sum += __shfl_xor(sum, off); sq += __shfl_xor(sq, off); }
  const int lane = tid & 63, wid = tid >> 6;
  if (lane == 0) { red[0][wid] = sum; red[1][wid] = sq; }
  __syncthreads();
  sum = red[0][0] + red[0][1] + red[0][2] + red[0][3];
  sq  = red[1][0] + red[1][1] + red[1][2] + red[1][3];
  const float mean = sum * (1.f / DD);
  const float var  = sq  * (1.f / DD) - mean * mean;
  const float rstd = rsqrtf(var + 1e-12f);
#pragma unroll
  for (int j = 0; j < 3; ++j) {
    int e = tid + j * 256;
    float o = (v[j] - mean) * rstd * g[e] + bt[e];
    hf[base + e] = o;
    hb[base + e] = f2bf(o);
  }
}

// ================= 8-phase 256x256 GEMM, K=768 (NT=12 K-tiles of 64) =================
// C[M,N] = A[M,768](bf16) @ Bw[N,768](bf16)^T + bias
// MODE 0: QKV fused (N=2304; sub=bn/3: Q,K row-major bf16; V transposed vT[b][h][d][s])
// MODE 1: FFN1 (N=3072; gelu, bf16 out)
// Schedule: per K-tile 4 phases (kk=q>>1 k-half, mh=q&1 M-half); 1 stage-unit
// ([256][32] = 16KB) per phase; counted vmcnt(4) once per tile (never 0 until tail);
// raw s_barrier (no compiler vmcnt-drain); setprio around MFMA cluster.
template<int MODE>
__global__ __launch_bounds__(512, 2)
void gemm8(const ushort* __restrict__ A, const ushort* __restrict__ Bw,
           const float* __restrict__ b0, const float* __restrict__ b1,
           const float* __restrict__ b2,
           ushort* __restrict__ o0, ushort* __restrict__ o1, ushort* __restrict__ o2)
{
  // [slot][khalf][row][kslot*8] ; each [256][32] unit is 16KB contiguous (glds linear dest)
  __shared__ ushort Asl[2][2][256][32];
  __shared__ ushort Bsl[2][2][256][32];

  const int tid = threadIdx.x;
  const int lane = tid & 63, wv = tid >> 6;
  const int wr = wv >> 2, wc = wv & 3;          // 2 M-waves x 4 N-waves
  const int fr = lane & 15, fg = lane >> 4;

  // bijective XCD swizzle (grid counts divisible by 8)
  int id = blockIdx.y * gridDim.x + blockIdx.x;
  const int chunk = (gridDim.x * gridDim.y) >> 3;
  id = (id & 7) * chunk + (id >> 3);
  const int bm = id & 31;                       // gridDim.x == 32
  const int bn = id >> 5;

  // staging lambdas: one unit = [256 rows][32 k] of one tensor at (kt, khalf)
  auto stA = [&](int kt, int kh) {
#pragma unroll
    for (int j = 0; j < 2; ++j) {
      const int slot = j * 512 + tid;
      const int row = slot >> 2;
      const int gks = (slot & 3) ^ ((row >> 1) & 3);   // inverse swizzle on global src
      const ushort* g = A + (size_t)(bm * 256 + row) * 768 + kt * 64 + kh * 32 + gks * 8;
      glds16(g, &Asl[kt & 1][kh][0][0] + (j * 512 + wv * 64) * 8);
    }
  };
  auto stB = [&](int kt, int kh) {
#pragma unroll
    for (int j = 0; j < 2; ++j) {
      const int slot = j * 512 + tid;
      const int row = slot >> 2;
      const int gks = (slot & 3) ^ ((row >> 1) & 3);
      const ushort* g = Bw + (size_t)(bn * 256 + row) * 768 + kt * 64 + kh * 32 + gks * 8;
      glds16(g, &Bsl[kt & 1][kh][0][0] + (j * 512 + wv * 64) * 8);
    }
  };

  f32x4 acc[8][4];
#pragma unroll
  for (int i = 0; i < 8; ++i)
#pragma unroll
    for (int j = 0; j < 4; ++j) acc[i][j] = f32x4{0.f, 0.f, 0.f, 0.f};

  // prologue: tile0 complete + tile1 kh0 (6 units, 12 loads); leave last 2 units in flight
  stA(0, 0); stB(0, 0); stA(0, 1); stB(0, 1); stA(1, 0); stB(1, 0);
  asm volatile("s_waitcnt vmcnt(4)" ::: "memory");
  asm volatile("s_barrier" ::: "memory");

  const int NT = 12;
  for (int kt = 0; kt < NT; ++kt) {
    const int slot = kt & 1;
#pragma unroll
    for (int q = 0; q < 4; ++q) {
      const int kk = q >> 1, mh = q & 1;
      // ds-load register subtiles (8 x ds_read_b128, swizzled)
      bf16x8 bf[4], af[4];
#pragma unroll
      for (int j = 0; j < 4; ++j) {
        const int row = wc * 64 + j * 16 + fr;
        bf[j] = *(const bf16x8*)&Bsl[slot][kk][row][(fg ^ ((row >> 1) & 3)) * 8];
      }
#pragma unroll
      for (int i = 0; i < 4; ++i) {
        const int row = wr * 128 + mh * 64 + i * 16 + fr;
        af[i] = *(const bf16x8*)&Asl[slot][kk][row][(fg ^ ((row >> 1) & 3)) * 8];
      }
      // stage one unit (region free: last read 2 phases ago)
      if (q == 0)      { if (kt + 1 < NT) stA(kt + 1, 1); }
      else if (q == 1) { if (kt + 1 < NT) stB(kt + 1, 1); }
      else if (q == 2) { if (kt + 2 < NT) stA(kt + 2, 0); }
      else             { if (kt + 2 < NT) stB(kt + 2, 0); }
      // counted wait once per tile, gating next tile's reads
      if (q == 3) {
        if (kt < NT - 2)       { asm volatile("s_waitcnt vmcnt(4)" ::: "memory"); }
        else if (kt == NT - 2) { asm volatile("s_waitcnt vmcnt(0)" ::: "memory"); }
      }
      asm volatile("s_barrier" ::: "memory");
      asm volatile("s_waitcnt lgkmcnt(0)" ::: "memory");
      __builtin_amdgcn_s_setprio(1);
#pragma unroll
      for (int i = 0; i < 4; ++i)
#pragma unroll
        for (int j = 0; j < 4; ++j)
          acc[mh * 4 + i][j] =
            __builtin_amdgcn_mfma_f32_16x16x32_bf16(bf[j], af[i], acc[mh * 4 + i][j], 0, 0, 0);
      __builtin_amdgcn_s_setprio(0);
      asm volatile("s_barrier" ::: "memory");
    }
  }

  // epilogue — swapped-operand layout: lane holds row m = ...+fr, cols n = ...+fg*4+r
  if (MODE == 0) {
    const int sub = bn / 3;                          // 0=Q 1=K 2=V
    const int cb = (bn - sub * 3) * 256 + wc * 64;   // col base within 768
    const float* bias = sub == 0 ? b0 : (sub == 1 ? b1 : b2);
    ushort* out = sub == 0 ? o0 : o1;
#pragma unroll
    for (int ig = 0; ig < 8; ++ig) {
      const int row_g = bm * 256 + wr * 128 + ig * 16 + fr;
#pragma unroll
      for (int j = 0; j < 4; ++j) {
        const int col = cb + j * 16 + fg * 4;
        const float4 bv4 = *(const float4*)&bias[col];
        const float v0 = acc[ig][j][0] + bv4.x;
        const float v1 = acc[ig][j][1] + bv4.y;
        const float v2 = acc[ig][j][2] + bv4.z;
        const float v3 = acc[ig][j][3] + bv4.w;
        if (sub < 2) {
          ushort4 o4; o4.x = f2bf(v0); o4.y = f2bf(v1); o4.z = f2bf(v2); o4.w = f2bf(v3);
          *(ushort4*)&out[(size_t)row_g * DD + col] = o4;
        } else {
          // V transposed: vT[((b*H + h)*DH + d)*S + s]
          const int b_ = row_g >> 9, s_ = row_g & 511;
          const int h_ = col >> 6, d0 = col & 63;
          ushort* vp = o2 + (((size_t)(b_ * HH + h_) * DHD + d0) * SS + s_);
          vp[0] = f2bf(v0); vp[SS] = f2bf(v1); vp[2 * SS] = f2bf(v2); vp[3 * SS] = f2bf(v3);
        }
      }
    }
  } else {
#pragma unroll
    for (int ig = 0; ig < 8; ++ig) {
      const int row_g = bm * 256 + wr * 128 + ig * 16 + fr;
#pragma unroll
      for (int j = 0; j < 4; ++j) {
        const int col = bn * 256 + wc * 64 + j * 16 + fg * 4;
        const float4 bv4 = *(const float4*)&b0[col];
        ushort4 o4;
        o4.x = f2bf(gelu_t(acc[ig][j][0] + bv4.x));
        o4.y = f2bf(gelu_t(acc[ig][j][1] + bv4.y));
        o4.z = f2bf(gelu_t(acc[ig][j][2] + bv4.z));
        o4.w = f2bf(gelu_t(acc[ig][j][3] + bv4.w));
        *(ushort4*)&o0[(size_t)row_g * FF + col] = o4;
      }
    }
  }
}

// ================= 2-phase 128x128 GEMM (O-proj, Wd: N=768) =================
// EPI 1: f32 out + bias
template<int EPI>
__global__ __launch_bounds__(256, 2)
void gemm_ker(const ushort* __restrict__ A, const ushort* __restrict__ Bw,
              const float* __restrict__ bias, void* __restrict__ Cout,
              int Ndim, int Kdim)
{
  __shared__ ushort As[2][128 * 32];
  __shared__ ushort Bs[2][128 * 32];

  int id = blockIdx.y * gridDim.x + blockIdx.x;
  const int chunk = (gridDim.x * gridDim.y) >> 3;
  id = (id & 7) * chunk + (id >> 3);
  const int bm = id & 63;
  const int bn = id >> 6;

  const int tid = threadIdx.x;
  const int l = tid & 63, w = tid >> 6;
  const int wm = w >> 1, wn = w & 1;
  const int fr = l & 15, fg = l >> 4;

  const int srow = l >> 2;
  const int scol = (l & 3) * 8;
  const ushort* Agl = A  + (size_t)(bm * 128 + w * 32 + srow) * Kdim + scol;
  const ushort* Bgl = Bw + (size_t)(bn * 128 + w * 32 + srow) * Kdim + scol;
  ushort* AsW = &As[0][(w * 32) * 32];
  ushort* BsW = &Bs[0][(w * 32) * 32];

  auto stage = [&](int buf, int kt) {
    const ushort* a = Agl + kt * 32;
    const ushort* b = Bgl + kt * 32;
    ushort* al = AsW + buf * 4096;
    ushort* bl = BsW + buf * 4096;
    glds16(a,                     al);
    glds16(a + 16 * (size_t)Kdim, al + 512);
    glds16(b,                     bl);
    glds16(b + 16 * (size_t)Kdim, bl + 512);
  };

  f32x4 acc[4][4];
#pragma unroll
  for (int i = 0; i < 4; ++i)
#pragma unroll
    for (int j = 0; j < 4; ++j) acc[i][j] = f32x4{0.f, 0.f, 0.f, 0.f};

  stage(0, 0);
  __syncthreads();
  const int nk = Kdim >> 5;
  int cur = 0;
  for (int kt = 0; kt < nk; ++kt) {
    if (kt + 1 < nk) stage(cur ^ 1, kt + 1);
    bf16x8 af[4], bfv[4];
#pragma unroll
    for (int i = 0; i < 4; ++i) af[i]  = *(const bf16x8*)&As[cur][(wm * 64 + i * 16 + fr) * 32 + fg * 8];
#pragma unroll
    for (int j = 0; j < 4; ++j) bfv[j] = *(const bf16x8*)&Bs[cur][(wn * 64 + j * 16 + fr) * 32 + fg * 8];
#pragma unroll
    for (int i = 0; i < 4; ++i)
#pragma unroll
      for (int j = 0; j < 4; ++j)
        acc[i][j] = __builtin_amdgcn_mfma_f32_16x16x32_bf16(af[i], bfv[j], acc[i][j], 0, 0, 0);
    __syncthreads();
    cur ^= 1;
  }

#pragma unroll
  for (int i = 0; i < 4; ++i) {
    const int row0 = bm * 128 + wm * 64 + i * 16 + fg * 4;
#pragma unroll
    for (int j = 0; j < 4; ++j) {
      const int col = bn * 128 + wn * 64 + j * 16 + fr;
      const float bv = bias[col];
#pragma unroll
      for (int r = 0; r < 4; ++r) {
        float v = acc[i][j][r] + bv;
        if (EPI == 1) ((float*)Cout)[(size_t)(row0 + r) * Ndim + col] = v;
        else          ((ushort*)Cout)[(size_t)(row0 + r) * Ndim + col] = f2bf(v);
      }
    }
  }
}

// ================= fused flash attention (V pre-transposed) =================
__global__ __launch_bounds__(256, 2)
void attn_kernel(const ushort* __restrict__ qb, const ushort* __restrict__ kb,
                 const ushort* __restrict__ vt, const float* __restrict__ relt,
                 const float* __restrict__ amask, ushort* __restrict__ ctxb)
{
  __shared__ ushort Kt[128][72];
  __shared__ ushort Vt[64][136];
  __shared__ ushort Pl[64][136];
  __shared__ float am_lds[512];
  __shared__ float rel_lds[1024];

  const int tid = threadIdx.x, lane = tid & 63, w = tid >> 6;

  int lin = blockIdx.y * gridDim.x + blockIdx.x;
  lin = (lin & 7) * 192 + (lin >> 3);
  const int qt = lin & 7;
  const int bh = lin >> 3;
  const int b = bh / HH, h = bh - b * HH;
  const int fr = lane & 15, fg = lane >> 4;

  for (int i = tid; i < 512; i += 256)
    am_lds[i] = (1.0f - amask[b * SS + i]) * -10000.0f;
  for (int i = tid; i < 1024; i += 256) {
    int d = i - 512;
    d = min(128, max(-128, d));
    rel_lds[i] = relt[(d + 128) * HH + h];
  }

  bf16x8 qf[2];
  {
    const int qrow = qt * 64 + w * 16 + fr;
    const ushort* p = qb + ((size_t)(b * SS + qrow) * DD) + h * DHD + fg * 8;
    qf[0] = *(const bf16x8*)p;
    qf[1] = *(const bf16x8*)(p + 32);
  }

  f32x4 o[4];
  float mrow[4], lrow[4];
#pragma unroll
  for (int r = 0; r < 4; ++r) { mrow[r] = -1e30f; lrow[r] = 0.f; }
#pragma unroll
  for (int d = 0; d < 4; ++d) o[d] = f32x4{0.f, 0.f, 0.f, 0.f};

  const int skr = tid >> 1;
  const int shd = (tid & 1) * 32;
  const int vrow = tid >> 2;
  const int vcg  = (tid & 3) * 32;
  const ushort* vgl = vt + ((size_t)bh * DHD + vrow) * SS + vcg;

  const int qg0 = qt * 64 + w * 16;

  for (int kt = 0; kt < 4; ++kt) {
    const size_t gbase = ((size_t)(b * SS + kt * 128 + skr) * DD) + h * DHD + shd;
    int4 kr0 = *(const int4*)(kb + gbase);
    int4 kr1 = *(const int4*)(kb + gbase + 8);
    int4 kr2 = *(const int4*)(kb + gbase + 16);
    int4 kr3 = *(const int4*)(kb + gbase + 24);
    const ushort* vp = vgl + kt * 128;
    int4 vr0 = *(const int4*)(vp);
    int4 vr1 = *(const int4*)(vp + 8);
    int4 vr2 = *(const int4*)(vp + 16);
    int4 vr3 = *(const int4*)(vp + 24);

    __syncthreads();
    *(int4*)&Kt[skr][shd]      = kr0;
    *(int4*)&Kt[skr][shd + 8]  = kr1;
    *(int4*)&Kt[skr][shd + 16] = kr2;
    *(int4*)&Kt[skr][shd + 24] = kr3;
    *(int4*)&Vt[vrow][vcg]      = vr0;
    *(int4*)&Vt[vrow][vcg + 8]  = vr1;
    *(int4*)&Vt[vrow][vcg + 16] = vr2;
    *(int4*)&Vt[vrow][vcg + 24] = vr3;
    __syncthreads();

    float sv[8][4];
    __builtin_amdgcn_s_setprio(1);
#pragma unroll
    for (int kc = 0; kc < 8; ++kc) {
      f32x4 s = f32x4{0.f, 0.f, 0.f, 0.f};
      bf16x8 kf0 = *(const bf16x8*)&Kt[kc * 16 + fr][fg * 8];
      bf16x8 kf1 = *(const bf16x8*)&Kt[kc * 16 + fr][32 + fg * 8];
      s = __builtin_amdgcn_mfma_f32_16x16x32_bf16(qf[0], kf0, s, 0, 0, 0);
      s = __builtin_amdgcn_mfma_f32_16x16x32_bf16(qf[1], kf1, s, 0, 0, 0);
      const int col = kt * 128 + kc * 16 + fr;
      const float am = am_lds[col];
      const int ridx = col - qg0 - fg * 4 + 512;
#pragma unroll
      for (int r = 0; r < 4; ++r)
        sv[kc][r] = s[r] * 0.125f + rel_lds[ridx - r] + am;
    }
    __builtin_amdgcn_s_setprio(0);

    float ef[4];
#pragma unroll
    for (int r = 0; r < 4; ++r) {
      float tmax = sv[0][r];
#pragma unroll
      for (int kc = 1; kc < 8; ++kc) tmax = fmaxf(tmax, sv[kc][r]);
#pragma unroll
      for (int off = 1; off < 16; off <<= 1) tmax = fmaxf(tmax, __shfl_xor(tmax, off));
      const float mnew = fmaxf(mrow[r], tmax);
      ef[r] = __expf(mrow[r] - mnew);
      float psum = 0.f;
      const int prow = w * 16 + fg * 4 + r;
#pragma unroll
      for (int kc = 0; kc < 8; ++kc) {
        float p = __expf(sv[kc][r] - mnew);
        psum += p;
        Pl[prow][kc * 16 + fr] = f2bf(p);
      }
#pragma unroll
      for (int off = 1; off < 16; off <<= 1) psum += __shfl_xor(psum, off);
      lrow[r] = lrow[r] * ef[r] + psum;
      mrow[r] = mnew;
    }
#pragma unroll
    for (int dc = 0; dc < 4; ++dc)
#pragma unroll
      for (int r = 0; r < 4; ++r) o[dc][r] *= ef[r];
    __syncthreads();

    __builtin_amdgcn_s_setprio(1);
#pragma unroll
    for (int dc = 0; dc < 4; ++dc)
#pragma unroll
      for (int ks = 0; ks < 4; ++ks) {
        bf16x8 pf = *(const bf16x8*)&Pl[w * 16 + fr][ks * 32 + fg * 8];
        bf16x8 vf = *(const bf16x8*)&Vt[dc * 16 + fr][ks * 32 + fg * 8];
        o[dc] = __builtin_amdgcn_mfma_f32_16x16x32_bf16(pf, vf, o[dc], 0, 0, 0);
      }
    __builtin_amdgcn_s_setprio(0);
  }

#pragma unroll
  for (int dc = 0; dc < 4; ++dc)
#pragma unroll
    for (int r = 0; r < 4; ++r) {
      const int qg = qt * 64 + w * 16 + fg * 4 + r;
      const float v = o[dc][r] / lrow[r];
      ctxb[((size_t)(b * SS + qg) * DD) + h * DHD + dc * 16 + fr] = f2bf(v);
    }
}

// ================= host launch =================
extern "C" void kernel_launch(void* const* d_in, const int* in_sizes, int n_in,
                              void* d_out, int out_size, void* d_ws, size_t ws_size,
                              hipStream_t stream) {
  const int*   ids   = (const int*)d_in[0];
  const float* amask = (const float*)d_in[1];
  const float* wemb  = (const float*)d_in[2];
  const float* pemb  = (const float*)d_in[3];
  const float* eln_w = (const float*)d_in[4];
  const float* eln_b = (const float*)d_in[5];
  const float* relt  = (const float*)d_in[6];
  const float* Wq    = (const float*)d_in[7];
  const float* bq    = (const float*)d_in[8];
  const float* Wk    = (const float*)d_in[9];
  const float* bk    = (const float*)d_in[10];
  const float* Wv    = (const float*)d_in[11];
  const float* bv    = (const float*)d_in[12];
  const float* Wo    = (const float*)d_in[13];
  const float* bo    = (const float*)d_in[14];
  const float* aln_w = (const float*)d_in[15];
  const float* aln_b = (const float*)d_in[16];
  const float* Wi    = (const float*)d_in[17];
  const float* bi    = (const float*)d_in[18];
  const float* Wd    = (const float*)d_in[19];
  const float* bd    = (const float*)d_in[20];
  const float* oln_w = (const float*)d_in[21];
  const float* oln_b = (const float*)d_in[22];

  size_t off = 0;
  auto carve = [&](size_t bytes) -> void* {
    void* r = (char*)d_ws + off;
    off += (bytes + 255) & ~(size_t)255;
    return r;
  };
  float*  hf     = (float*) carve((size_t)MM * DD * 4);
  ushort* hb     = (ushort*)carve((size_t)MM * DD * 2);
  ushort* qbuf   = (ushort*)carve((size_t)MM * DD * 2);
  ushort* kbuf   = (ushort*)carve((size_t)MM * DD * 2);
  ushort* vbuf   = (ushort*)carve((size_t)MM * DD * 2);   // vT[b][h][d][s]
  ushort* ctxb   = (ushort*)carve((size_t)MM * DD * 2);
  float*  gout   = (float*) carve((size_t)MM * DD * 4);
  ushort* interb = (ushort*)carve((size_t)MM * FF * 2);

  ushort* wA = interb;   // Wq,Wk,Wv,Wo bf16 in interb's dead window
  ushort* wB = qbuf;     // Wi,Wd bf16 in qbuf's dead window (after attn)
  const int PD = DD * DD;
  const int PF = FF * DD;

  embed_ln_kernel<<<MM, 256, 0, stream>>>(ids, wemb, pemb, eln_w, eln_b, hf, hb);

  const dim3 gQKV(MM / 256, 9);               // 32 x 9 (N=2304)
  const dim3 gF1(MM / 256, FF / 256);         // 32 x 12
  const dim3 gD(MM / 128, DD / 128);          // 64 x 6
  const dim3 gA(SS / 64, BB * HH);            // 8 x 192
  const dim3 gCA(PD / 1024, 4);
  const dim3 gCB(PF / 1024, 2);

  for (int l = 0; l < LL; ++l) {
    const size_t wo  = (size_t)l * PD;
    const size_t wio = (size_t)l * PF;

    convw4<<<gCA, 256, 0, stream>>>(Wq + wo, Wk + wo, Wv + wo, Wo + wo, wA, PD);

    gemm8<0><<<gQKV, 512, 0, stream>>>(hb, wA, bq + l * DD, bk + l * DD, bv + l * DD,
                                       qbuf, kbuf, vbuf);

    attn_kernel<<<gA, 256, 0, stream>>>(qbuf, kbuf, vbuf, relt, amask, ctxb);

    convw4<<<gCB, 256, 0, stream>>>(Wi + wio, Wd + wio, Wi + wio, Wi + wio, wB, PF);

    gemm_ker<1><<<gD, 256, 0, stream>>>(ctxb, wA + 3 * PD, bo + l * DD, gout, DD, DD);
    add_ln_kernel<<<MM, 256, 0, stream>>>(hf, gout, aln_w + l * DD, aln_b + l * DD, hf, hb);

    gemm8<1><<<gF1, 512, 0, stream>>>(hb, wB, bi + l * FF, nullptr, nullptr,
                                      interb, nullptr, nullptr);
    gemm_ker<1><<<gD, 256, 0, stream>>>(interb, wB + PF, bd + l * DD, gout, DD, FF);

    float* outp = (l == LL - 1) ? (float*)d_out : hf;
    add_ln_kernel<<<MM, 256, 0, stream>>>(hf, gout, oln_w + l * DD, oln_b + l * DD, outp, hb);
  }
}

// Round 8
// 3737.607 us; speedup vs baseline: 1.1117x; 1.1117x over previous
//
#include <hip/hip_runtime.h>
#include <cstdint>
#include <cstddef>

// ---------------- config ----------------
#define BB 16
#define SS 512
#define DD 768
#define HH 12
#define FF 3072
#define LL 12
#define DHD 64
#define MM (BB*SS)   // 8192 rows

typedef __attribute__((ext_vector_type(8))) short bf16x8;
typedef __attribute__((ext_vector_type(4))) float f32x4;

__device__ __forceinline__ ushort f2bf(float f) {
  union { float f; uint32_t u; } x; x.f = f;
  uint32_t r = x.u + 0x7FFFu + ((x.u >> 16) & 1u);
  return (ushort)(r >> 16);
}

__device__ __forceinline__ void glds16(const ushort* g, ushort* l) {
  __builtin_amdgcn_global_load_lds((__attribute__((address_space(1))) void*)g,
                                   (__attribute__((address_space(3))) void*)l,
                                   16, 0, 0);
}

__device__ __forceinline__ float gelu_t(float v) {
  // tanh-form gelu; |err| vs exact erf-gelu < ~3e-4, below bf16 ulp here
  float y = 0.7978845608f * (v + 0.044715f * v * v * v);
  y = fminf(fmaxf(y, -15.f), 15.f);
  float e = __expf(2.f * y);
  return 0.5f * v * (2.f - 2.f / (e + 1.f));
}

// ================= weight f32 -> bf16 conversion (up to 4 tensors) =================
__global__ __launch_bounds__(256)
void convw4(const float* __restrict__ s0, const float* __restrict__ s1,
            const float* __restrict__ s2, const float* __restrict__ s3,
            ushort* __restrict__ dst, int per)
{
  const float* s = blockIdx.y == 0 ? s0 : blockIdx.y == 1 ? s1 : blockIdx.y == 2 ? s2 : s3;
  const int i = (blockIdx.x * 256 + threadIdx.x) * 4;
  if (i >= per) return;
  const float4 v = *(const float4*)(s + i);
  ushort4 o;
  o.x = f2bf(v.x); o.y = f2bf(v.y); o.z = f2bf(v.z); o.w = f2bf(v.w);
  *(ushort4*)(dst + (size_t)blockIdx.y * per + i) = o;
}

// ================= embedding + LayerNorm =================
__global__ __launch_bounds__(256)
void embed_ln_kernel(const int* __restrict__ ids, const float* __restrict__ wemb,
                     const float* __restrict__ pemb, const float* __restrict__ g,
                     const float* __restrict__ bt, float* __restrict__ hf,
                     ushort* __restrict__ hb)
{
  const int row = blockIdx.x;
  const int s = row & (SS - 1);
  const int id = ids[row];
  const float* wp = wemb + (size_t)id * DD;
  const float* pp = pemb + (size_t)s * DD;
  const int tid = threadIdx.x;
  float v[3]; float sum = 0.f, sq = 0.f;
#pragma unroll
  for (int j = 0; j < 3; ++j) {
    int e = tid + j * 256;
    v[j] = wp[e] + pp[e];
    sum += v[j]; sq += v[j] * v[j];
  }
  __shared__ float red[2][4];
#pragma unroll
  for (int off = 32; off >= 1; off >>= 1) { sum += __shfl_xor(sum, off); sq += __shfl_xor(sq, off); }
  const int lane = tid & 63, wid = tid >> 6;
  if (lane == 0) { red[0][wid] = sum; red[1][wid] = sq; }
  __syncthreads();
  sum = red[0][0] + red[0][1] + red[0][2] + red[0][3];
  sq  = red[1][0] + red[1][1] + red[1][2] + red[1][3];
  const float mean = sum * (1.f / DD);
  const float var  = sq  * (1.f / DD) - mean * mean;
  const float rstd = rsqrtf(var + 1e-12f);
  const size_t base = (size_t)row * DD;
#pragma unroll
  for (int j = 0; j < 3; ++j) {
    int e = tid + j * 256;
    float o = (v[j] - mean) * rstd * g[e] + bt[e];
    hf[base + e] = o;
    hb[base + e] = f2bf(o);
  }
}

// ================= residual add + LayerNorm =================
__global__ __launch_bounds__(256)
void add_ln_kernel(const float* __restrict__ res, const float* __restrict__ add,
                   const float* __restrict__ g, const float* __restrict__ bt,
                   float* __restrict__ hf, ushort* __restrict__ hb)
{
  const int row = blockIdx.x;
  const int tid = threadIdx.x;
  const size_t base = (size_t)row * DD;
  float v[3]; float sum = 0.f, sq = 0.f;
#pragma unroll
  for (int j = 0; j < 3; ++j) {
    int e = tid + j * 256;
    v[j] = res[base + e] + add[base + e];
    sum += v[j]; sq += v[j] * v[j];
  }
  __shared__ float red[2][4];
#pragma unroll
  for (int off = 32; off >= 1; off >>= 1) { sum += __shfl_xor(sum, off); sq += __shfl_xor(sq, off); }
  const int lane = tid & 63, wid = tid >> 6;
  if (lane == 0) { red[0][wid] = sum; red[1][wid] = sq; }
  __syncthreads();
  sum = red[0][0] + red[0][1] + red[0][2] + red[0][3];
  sq  = red[1][0] + red[1][1] + red[1][2] + red[1][3];
  const float mean = sum * (1.f / DD);
  const float var  = sq  * (1.f / DD) - mean * mean;
  const float rstd = rsqrtf(var + 1e-12f);
#pragma unroll
  for (int j = 0; j < 3; ++j) {
    int e = tid + j * 256;
    float o = (v[j] - mean) * rstd * g[e] + bt[e];
    hf[base + e] = o;
    hb[base + e] = f2bf(o);
  }
}

// ================= GEMM: C[M,N] = A[M,K](bf16) @ Bw[N,K](bf16)^T + bias =================
// 128x128 tile, BK=32, TRIPLE-buffered LDS (48KB), counted vmcnt(4) per K-step,
// raw s_barrier (no compiler vmcnt-0 drain), XOR-swizzled staging (0 bank conflicts,
// HW-verified), swapped-operand MFMA -> vectorized epilogue.
// Multi-sub along N (QKV fusion): grid.y = nsub*nblk, each sub is [M, nblk*128].
// EPI 0: bf16 out; 1: f32 out; 2: bf16 out + gelu. TRV: sub==2 writes vT[b][h][d][s].
template<int EPI, bool TRV>
__global__ __launch_bounds__(256, 3)
void gemm_ker(const ushort* __restrict__ A,
              const ushort* __restrict__ B0, const ushort* __restrict__ B1,
              const ushort* __restrict__ B2,
              const float* __restrict__ bias0, const float* __restrict__ bias1,
              const float* __restrict__ bias2,
              void* __restrict__ C0, void* __restrict__ C1, void* __restrict__ C2,
              int Kdim, int nblk)
{
  __shared__ ushort As[3][128 * 32];
  __shared__ ushort Bs[3][128 * 32];

  // bijective XCD swizzle (all grids divisible by 8)
  int id = blockIdx.y * gridDim.x + blockIdx.x;
  const int chunk = (gridDim.x * gridDim.y) >> 3;
  id = (id & 7) * chunk + (id >> 3);
  const int bm = id & 63;                 // gridDim.x == 64
  const int bnAll = id >> 6;
  const int sub = bnAll / nblk;
  const int bn = bnAll - sub * nblk;

  const ushort* Bw  = sub == 0 ? B0 : (sub == 1 ? B1 : B2);
  const float* bias = sub == 0 ? bias0 : (sub == 1 ? bias1 : bias2);
  const int Ndim = nblk * 128;

  const int tid = threadIdx.x;
  const int l = tid & 63, w = tid >> 6;
  const int wm = w >> 1, wn = w & 1;
  const int fr = l & 15, fg = l >> 4;

  // --- staging: rows are 64B (4 slots of 16B); pre-swizzle global col-slot by
  // (row>>1)&3 == (l>>3)&3 (lane-constant). LDS dest stays linear (glds16 rule).
  const int srow_in = l >> 2;                         // 0..15 within 16-row chunk
  const int gks = ((l & 3) ^ ((l >> 3) & 3)) * 8;     // swizzled global col
  const ushort* Agl0 = A  + (size_t)(bm * 128 + w * 16 + srow_in) * Kdim + gks;
  const ushort* Agl1 = Agl0 + (size_t)64 * Kdim;
  const ushort* Bgl0 = Bw + (size_t)(bn * 128 + w * 16 + srow_in) * Kdim + gks;
  const ushort* Bgl1 = Bgl0 + (size_t)64 * Kdim;

  auto stage = [&](int b, int kt) {
    const int ko = kt * 32;
    ushort* al = &As[b][w * 64 * 8];          // wave's 64-slot chunk, j=0
    ushort* bl = &Bs[b][w * 64 * 8];
    glds16(Agl0 + ko, al);
    glds16(Agl1 + ko, al + 256 * 8);          // j=1 chunk (+256 slots)
    glds16(Bgl0 + ko, bl);
    glds16(Bgl1 + ko, bl + 256 * 8);
  };

  // ds_read swizzle: frag k-slot = fg ^ ((row>>1)&3) = fg ^ ((fr>>1)&3) (lane-const)
  const int se = (fg ^ ((fr >> 1) & 3)) * 8;

  f32x4 acc[4][4];
#pragma unroll
  for (int i = 0; i < 4; ++i)
#pragma unroll
    for (int j = 0; j < 4; ++j) acc[i][j] = f32x4{0.f, 0.f, 0.f, 0.f};

  // prologue: stage tiles 0 and 1; wait only for tile 0
  stage(0, 0);
  stage(1, 1);
  asm volatile("s_waitcnt vmcnt(4)" ::: "memory");
  asm volatile("s_barrier" ::: "memory");

  const int nk = Kdim >> 5;
  for (int kt = 0; kt < nk; ++kt) {
    const int rb = kt % 3;
    if (kt + 2 < nk) stage((kt + 2) % 3, kt + 2);

    bf16x8 af[4], bfv[4];
#pragma unroll
    for (int i = 0; i < 4; ++i)
      af[i]  = *(const bf16x8*)&As[rb][(wm * 64 + i * 16 + fr) * 32 + se];
#pragma unroll
    for (int j = 0; j < 4; ++j)
      bfv[j] = *(const bf16x8*)&Bs[rb][(wn * 64 + j * 16 + fr) * 32 + se];

    __builtin_amdgcn_s_setprio(1);
#pragma unroll
    for (int i = 0; i < 4; ++i)
#pragma unroll
      for (int j = 0; j < 4; ++j)
        acc[i][j] = __builtin_amdgcn_mfma_f32_16x16x32_bf16(bfv[j], af[i], acc[i][j], 0, 0, 0);
    __builtin_amdgcn_s_setprio(0);

    if (kt + 1 < nk) {
      if (kt + 2 < nk) { asm volatile("s_waitcnt vmcnt(4)" ::: "memory"); }
      else             { asm volatile("s_waitcnt vmcnt(0)" ::: "memory"); }
      asm volatile("s_barrier" ::: "memory");
    }
  }

  // epilogue — swapped-operand layout: lane holds M-row (fr), 4 consecutive N-cols (fg*4+reg)
#pragma unroll
  for (int i = 0; i < 4; ++i) {
    const int row_g = bm * 128 + wm * 64 + i * 16 + fr;
#pragma unroll
    for (int j = 0; j < 4; ++j) {
      const int col = bn * 128 + wn * 64 + j * 16 + fg * 4;
      const float4 bv4 = *(const float4*)&bias[col];
      const float v0 = acc[i][j][0] + bv4.x;
      const float v1 = acc[i][j][1] + bv4.y;
      const float v2 = acc[i][j][2] + bv4.z;
      const float v3 = acc[i][j][3] + bv4.w;
      if (TRV && sub == 2) {
        // V transposed: vT[((b*H + h)*DH + d)*S + s]; v0..v3 are d, d+1, d+2, d+3
        const int b_ = row_g >> 9, s_ = row_g & 511;
        const int h_ = col >> 6, d0 = col & 63;
        ushort* vp = (ushort*)C2 + (((size_t)(b_ * HH + h_) * DHD + d0) * SS + s_);
        vp[0] = f2bf(v0); vp[SS] = f2bf(v1); vp[2 * SS] = f2bf(v2); vp[3 * SS] = f2bf(v3);
      } else if (EPI == 1) {
        void* Cout = sub == 0 ? C0 : (sub == 1 ? C1 : C2);
        float4 o4; o4.x = v0; o4.y = v1; o4.z = v2; o4.w = v3;
        *(float4*)&((float*)Cout)[(size_t)row_g * Ndim + col] = o4;
      } else if (EPI == 2) {
        ushort4 o4;
        o4.x = f2bf(gelu_t(v0)); o4.y = f2bf(gelu_t(v1));
        o4.z = f2bf(gelu_t(v2)); o4.w = f2bf(gelu_t(v3));
        *(ushort4*)&((ushort*)C0)[(size_t)row_g * Ndim + col] = o4;
      } else {
        void* Cout = sub == 0 ? C0 : (sub == 1 ? C1 : C2);
        ushort4 o4;
        o4.x = f2bf(v0); o4.y = f2bf(v1); o4.z = f2bf(v2); o4.w = f2bf(v3);
        *(ushort4*)&((ushort*)Cout)[(size_t)row_g * Ndim + col] = o4;
      }
    }
  }
}

// ================= fused flash attention (V pre-transposed) =================
__global__ __launch_bounds__(256, 2)
void attn_kernel(const ushort* __restrict__ qb, const ushort* __restrict__ kb,
                 const ushort* __restrict__ vt, const float* __restrict__ relt,
                 const float* __restrict__ amask, ushort* __restrict__ ctxb)
{
  __shared__ ushort Kt[128][72];
  __shared__ ushort Vt[64][136];
  __shared__ ushort Pl[64][136];
  __shared__ float am_lds[512];
  __shared__ float rel_lds[1024];

  const int tid = threadIdx.x, lane = tid & 63, w = tid >> 6;

  int lin = blockIdx.y * gridDim.x + blockIdx.x;
  lin = (lin & 7) * 192 + (lin >> 3);
  const int qt = lin & 7;
  const int bh = lin >> 3;
  const int b = bh / HH, h = bh - b * HH;
  const int fr = lane & 15, fg = lane >> 4;

  for (int i = tid; i < 512; i += 256)
    am_lds[i] = (1.0f - amask[b * SS + i]) * -10000.0f;
  for (int i = tid; i < 1024; i += 256) {
    int d = i - 512;
    d = min(128, max(-128, d));
    rel_lds[i] = relt[(d + 128) * HH + h];
  }

  bf16x8 qf[2];
  {
    const int qrow = qt * 64 + w * 16 + fr;
    const ushort* p = qb + ((size_t)(b * SS + qrow) * DD) + h * DHD + fg * 8;
    qf[0] = *(const bf16x8*)p;
    qf[1] = *(const bf16x8*)(p + 32);
  }

  f32x4 o[4];
  float mrow[4], lrow[4];
#pragma unroll
  for (int r = 0; r < 4; ++r) { mrow[r] = -1e30f; lrow[r] = 0.f; }
#pragma unroll
  for (int d = 0; d < 4; ++d) o[d] = f32x4{0.f, 0.f, 0.f, 0.f};

  const int skr = tid >> 1;
  const int shd = (tid & 1) * 32;
  const int vrow = tid >> 2;
  const int vcg  = (tid & 3) * 32;
  const ushort* vgl = vt + ((size_t)bh * DHD + vrow) * SS + vcg;

  const int qg0 = qt * 64 + w * 16;

  for (int kt = 0; kt < 4; ++kt) {
    const size_t gbase = ((size_t)(b * SS + kt * 128 + skr) * DD) + h * DHD + shd;
    int4 kr0 = *(const int4*)(kb + gbase);
    int4 kr1 = *(const int4*)(kb + gbase + 8);
    int4 kr2 = *(const int4*)(kb + gbase + 16);
    int4 kr3 = *(const int4*)(kb + gbase + 24);
    const ushort* vp = vgl + kt * 128;
    int4 vr0 = *(const int4*)(vp);
    int4 vr1 = *(const int4*)(vp + 8);
    int4 vr2 = *(const int4*)(vp + 16);
    int4 vr3 = *(const int4*)(vp + 24);

    __syncthreads();
    *(int4*)&Kt[skr][shd]      = kr0;
    *(int4*)&Kt[skr][shd + 8]  = kr1;
    *(int4*)&Kt[skr][shd + 16] = kr2;
    *(int4*)&Kt[skr][shd + 24] = kr3;
    *(int4*)&Vt[vrow][vcg]      = vr0;
    *(int4*)&Vt[vrow][vcg + 8]  = vr1;
    *(int4*)&Vt[vrow][vcg + 16] = vr2;
    *(int4*)&Vt[vrow][vcg + 24] = vr3;
    __syncthreads();

    float sv[8][4];
    __builtin_amdgcn_s_setprio(1);
#pragma unroll
    for (int kc = 0; kc < 8; ++kc) {
      f32x4 s = f32x4{0.f, 0.f, 0.f, 0.f};
      bf16x8 kf0 = *(const bf16x8*)&Kt[kc * 16 + fr][fg * 8];
      bf16x8 kf1 = *(const bf16x8*)&Kt[kc * 16 + fr][32 + fg * 8];
      s = __builtin_amdgcn_mfma_f32_16x16x32_bf16(qf[0], kf0, s, 0, 0, 0);
      s = __builtin_amdgcn_mfma_f32_16x16x32_bf16(qf[1], kf1, s, 0, 0, 0);
      const int col = kt * 128 + kc * 16 + fr;
      const float am = am_lds[col];
      const int ridx = col - qg0 - fg * 4 + 512;
#pragma unroll
      for (int r = 0; r < 4; ++r)
        sv[kc][r] = s[r] * 0.125f + rel_lds[ridx - r] + am;
    }
    __builtin_amdgcn_s_setprio(0);

    float ef[4];
#pragma unroll
    for (int r = 0; r < 4; ++r) {
      float tmax = sv[0][r];
#pragma unroll
      for (int kc = 1; kc < 8; ++kc) tmax = fmaxf(tmax, sv[kc][r]);
#pragma unroll
      for (int off = 1; off < 16; off <<= 1) tmax = fmaxf(tmax, __shfl_xor(tmax, off));
      const float mnew = fmaxf(mrow[r], tmax);
      ef[r] = __expf(mrow[r] - mnew);
      float psum = 0.f;
      const int prow = w * 16 + fg * 4 + r;
#pragma unroll
      for (int kc = 0; kc < 8; ++kc) {
        float p = __expf(sv[kc][r] - mnew);
        psum += p;
        Pl[prow][kc * 16 + fr] = f2bf(p);
      }
#pragma unroll
      for (int off = 1; off < 16; off <<= 1) psum += __shfl_xor(psum, off);
      lrow[r] = lrow[r] * ef[r] + psum;
      mrow[r] = mnew;
    }
#pragma unroll
    for (int dc = 0; dc < 4; ++dc)
#pragma unroll
      for (int r = 0; r < 4; ++r) o[dc][r] *= ef[r];
    __syncthreads();

    __builtin_amdgcn_s_setprio(1);
#pragma unroll
    for (int dc = 0; dc < 4; ++dc)
#pragma unroll
      for (int ks = 0; ks < 4; ++ks) {
        bf16x8 pf = *(const bf16x8*)&Pl[w * 16 + fr][ks * 32 + fg * 8];
        bf16x8 vf = *(const bf16x8*)&Vt[dc * 16 + fr][ks * 32 + fg * 8];
        o[dc] = __builtin_amdgcn_mfma_f32_16x16x32_bf16(pf, vf, o[dc], 0, 0, 0);
      }
    __builtin_amdgcn_s_setprio(0);
  }

#pragma unroll
  for (int dc = 0; dc < 4; ++dc)
#pragma unroll
    for (int r = 0; r < 4; ++r) {
      const int qg = qt * 64 + w * 16 + fg * 4 + r;
      const float v = o[dc][r] / lrow[r];
      ctxb[((size_t)(b * SS + qg) * DD) + h * DHD + dc * 16 + fr] = f2bf(v);
    }
}

// ================= host launch =================
extern "C" void kernel_launch(void* const* d_in, const int* in_sizes, int n_in,
                              void* d_out, int out_size, void* d_ws, size_t ws_size,
                              hipStream_t stream) {
  const int*   ids   = (const int*)d_in[0];
  const float* amask = (const float*)d_in[1];
  const float* wemb  = (const float*)d_in[2];
  const float* pemb  = (const float*)d_in[3];
  const float* eln_w = (const float*)d_in[4];
  const float* eln_b = (const float*)d_in[5];
  const float* relt  = (const float*)d_in[6];
  const float* Wq    = (const float*)d_in[7];
  const float* bq    = (const float*)d_in[8];
  const float* Wk    = (const float*)d_in[9];
  const float* bk    = (const float*)d_in[10];
  const float* Wv    = (const float*)d_in[11];
  const float* bv    = (const float*)d_in[12];
  const float* Wo    = (const float*)d_in[13];
  const float* bo    = (const float*)d_in[14];
  const float* aln_w = (const float*)d_in[15];
  const float* aln_b = (const float*)d_in[16];
  const float* Wi    = (const float*)d_in[17];
  const float* bi    = (const float*)d_in[18];
  const float* Wd    = (const float*)d_in[19];
  const float* bd    = (const float*)d_in[20];
  const float* oln_w = (const float*)d_in[21];
  const float* oln_b = (const float*)d_in[22];

  size_t off = 0;
  auto carve = [&](size_t bytes) -> void* {
    void* r = (char*)d_ws + off;
    off += (bytes + 255) & ~(size_t)255;
    return r;
  };
  float*  hf     = (float*) carve((size_t)MM * DD * 4);
  ushort* hb     = (ushort*)carve((size_t)MM * DD * 2);
  ushort* qbuf   = (ushort*)carve((size_t)MM * DD * 2);
  ushort* kbuf   = (ushort*)carve((size_t)MM * DD * 2);
  ushort* vbuf   = (ushort*)carve((size_t)MM * DD * 2);   // vT[b][h][d][s]
  ushort* ctxb   = (ushort*)carve((size_t)MM * DD * 2);
  float*  gout   = (float*) carve((size_t)MM * DD * 4);
  ushort* interb = (ushort*)carve((size_t)MM * FF * 2);

  ushort* wA = interb;   // Wq,Wk,Wv,Wo bf16 in interb's dead window
  ushort* wB = qbuf;     // Wi,Wd bf16 in qbuf's dead window (after attn)
  const int PD = DD * DD;
  const int PF = FF * DD;

  embed_ln_kernel<<<MM, 256, 0, stream>>>(ids, wemb, pemb, eln_w, eln_b, hf, hb);

  const dim3 gQKV(MM / 128, 3 * (DD / 128));  // 64 x 18
  const dim3 gD(MM / 128, DD / 128);          // 64 x 6
  const dim3 gF(MM / 128, FF / 128);          // 64 x 24
  const dim3 gA(SS / 64, BB * HH);            // 8 x 192
  const dim3 gCA(PD / 1024, 4);
  const dim3 gCB(PF / 1024, 2);

  for (int l = 0; l < LL; ++l) {
    const size_t wo  = (size_t)l * PD;
    const size_t wio = (size_t)l * PF;

    convw4<<<gCA, 256, 0, stream>>>(Wq + wo, Wk + wo, Wv + wo, Wo + wo, wA, PD);

    gemm_ker<0, true><<<gQKV, 256, 0, stream>>>(hb, wA, wA + PD, wA + 2 * PD,
                                                bq + l * DD, bk + l * DD, bv + l * DD,
                                                qbuf, kbuf, vbuf, DD, DD / 128);

    attn_kernel<<<gA, 256, 0, stream>>>(qbuf, kbuf, vbuf, relt, amask, ctxb);

    convw4<<<gCB, 256, 0, stream>>>(Wi + wio, Wd + wio, Wi + wio, Wi + wio, wB, PF);

    gemm_ker<1, false><<<gD, 256, 0, stream>>>(ctxb, wA + 3 * PD, wA + 3 * PD, wA + 3 * PD,
                                               bo + l * DD, bo + l * DD, bo + l * DD,
                                               gout, gout, gout, DD, DD / 128);
    add_ln_kernel<<<MM, 256, 0, stream>>>(hf, gout, aln_w + l * DD, aln_b + l * DD, hf, hb);

    gemm_ker<2, false><<<gF, 256, 0, stream>>>(hb, wB, wB, wB,
                                               bi + l * FF, bi + l * FF, bi + l * FF,
                                               interb, interb, interb, DD, FF / 128);
    gemm_ker<1, false><<<gD, 256, 0, stream>>>(interb, wB + PF, wB + PF, wB + PF,
                                               bd + l * DD, bd + l * DD, bd + l * DD,
                                               gout, gout, gout, FF, DD / 128);

    float* outp = (l == LL - 1) ? (float*)d_out : hf;
    add_ln_kernel<<<MM, 256, 0, stream>>>(hf, gout, oln_w + l * DD, oln_b + l * DD, outp, hb);
  }
}

// Round 9
// 3632.223 us; speedup vs baseline: 1.1439x; 1.0290x over previous
//
#include <hip/hip_runtime.h>
#include <cstdint>
#include <cstddef>

// ---------------- config ----------------
#define BB 16
#define SS 512
#define DD 768
#define HH 12
#define FF 3072
#define LL 12
#define DHD 64
#define MM (BB*SS)   // 8192 rows

typedef __attribute__((ext_vector_type(8))) short bf16x8;
typedef __attribute__((ext_vector_type(4))) float f32x4;

__device__ __forceinline__ ushort f2bf(float f) {
  union { float f; uint32_t u; } x; x.f = f;
  uint32_t r = x.u + 0x7FFFu + ((x.u >> 16) & 1u);
  return (ushort)(r >> 16);
}

__device__ __forceinline__ void glds16(const ushort* g, ushort* l) {
  __builtin_amdgcn_global_load_lds((__attribute__((address_space(1))) void*)g,
                                   (__attribute__((address_space(3))) void*)l,
                                   16, 0, 0);
}

__device__ __forceinline__ float gelu_t(float v) {
  float y = 0.7978845608f * (v + 0.044715f * v * v * v);
  y = fminf(fmaxf(y, -15.f), 15.f);
  float e = __expf(2.f * y);
  return 0.5f * v * (2.f - 2.f / (e + 1.f));
}

// ================= weight f32 -> bf16 conversion (6 tensors, one dispatch) ==========
__global__ __launch_bounds__(256)
void convw6(const float* __restrict__ s0, const float* __restrict__ s1,
            const float* __restrict__ s2, const float* __restrict__ s3,
            const float* __restrict__ s4, const float* __restrict__ s5,
            ushort* __restrict__ dA, ushort* __restrict__ dB, int perD, int perF)
{
  const int y = blockIdx.y;
  const int per = (y < 4) ? perD : perF;
  const int i = (blockIdx.x * 256 + threadIdx.x) * 4;
  if (i >= per) return;
  const float* s = y == 0 ? s0 : y == 1 ? s1 : y == 2 ? s2 : y == 3 ? s3 : y == 4 ? s4 : s5;
  ushort* dst = (y < 4) ? (dA + (size_t)y * perD) : (dB + (size_t)(y - 4) * perF);
  const float4 v = *(const float4*)(s + i);
  ushort4 o;
  o.x = f2bf(v.x); o.y = f2bf(v.y); o.z = f2bf(v.z); o.w = f2bf(v.w);
  *(ushort4*)(dst + i) = o;
}

// ================= embedding + LayerNorm =================
__global__ __launch_bounds__(256)
void embed_ln_kernel(const int* __restrict__ ids, const float* __restrict__ wemb,
                     const float* __restrict__ pemb, const float* __restrict__ g,
                     const float* __restrict__ bt, float* __restrict__ hf,
                     ushort* __restrict__ hb)
{
  const int row = blockIdx.x;
  const int s = row & (SS - 1);
  const int id = ids[row];
  const float* wp = wemb + (size_t)id * DD;
  const float* pp = pemb + (size_t)s * DD;
  const int tid = threadIdx.x;
  float v[3]; float sum = 0.f, sq = 0.f;
#pragma unroll
  for (int j = 0; j < 3; ++j) {
    int e = tid + j * 256;
    v[j] = wp[e] + pp[e];
    sum += v[j]; sq += v[j] * v[j];
  }
  __shared__ float red[2][4];
#pragma unroll
  for (int off = 32; off >= 1; off >>= 1) { sum += __shfl_xor(sum, off); sq += __shfl_xor(sq, off); }
  const int lane = tid & 63, wid = tid >> 6;
  if (lane == 0) { red[0][wid] = sum; red[1][wid] = sq; }
  __syncthreads();
  sum = red[0][0] + red[0][1] + red[0][2] + red[0][3];
  sq  = red[1][0] + red[1][1] + red[1][2] + red[1][3];
  const float mean = sum * (1.f / DD);
  const float var  = sq  * (1.f / DD) - mean * mean;
  const float rstd = rsqrtf(var + 1e-12f);
  const size_t base = (size_t)row * DD;
#pragma unroll
  for (int j = 0; j < 3; ++j) {
    int e = tid + j * 256;
    float o = (v[j] - mean) * rstd * g[e] + bt[e];
    hf[base + e] = o;
    hb[base + e] = f2bf(o);
  }
}

// ================= residual + two split-K partials + LayerNorm =================
__global__ __launch_bounds__(256)
void add_ln2_kernel(const float* __restrict__ res, const float* __restrict__ p0,
                    const float* __restrict__ p1, const float* __restrict__ g,
                    const float* __restrict__ bt, float* __restrict__ hf,
                    ushort* __restrict__ hb)
{
  const int row = blockIdx.x;
  const int tid = threadIdx.x;
  const size_t base = (size_t)row * DD;
  float v[3]; float sum = 0.f, sq = 0.f;
#pragma unroll
  for (int j = 0; j < 3; ++j) {
    int e = tid + j * 256;
    v[j] = res[base + e] + p0[base + e] + p1[base + e];
    sum += v[j]; sq += v[j] * v[j];
  }
  __shared__ float red[2][4];
#pragma unroll
  for (int off = 32; off >= 1; off >>= 1) { sum += __shfl_xor(sum, off); sq += __shfl_xor(sq, off); }
  const int lane = tid & 63, wid = tid >> 6;
  if (lane == 0) { red[0][wid] = sum; red[1][wid] = sq; }
  __syncthreads();
  sum = red[0][0] + red[0][1] + red[0][2] + red[0][3];
  sq  = red[1][0] + red[1][1] + red[1][2] + red[1][3];
  const float mean = sum * (1.f / DD);
  const float var  = sq  * (1.f / DD) - mean * mean;
  const float rstd = rsqrtf(var + 1e-12f);
#pragma unroll
  for (int j = 0; j < 3; ++j) {
    int e = tid + j * 256;
    float o = (v[j] - mean) * rstd * g[e] + bt[e];
    hf[base + e] = o;
    hb[base + e] = f2bf(o);
  }
}

// ================= GEMM: C[M,N] = A[M,K](bf16) @ Bw[N,K](bf16)^T + bias =================
// 128x128 tile, BK=32, triple-buffered, counted vmcnt(4), raw s_barrier,
// XOR-swizzled staging (0 bank conflicts), swapped-operand MFMA.
// EPI 0: bf16 out; 2: bf16 out + gelu. TRV: sub==2 writes vT[b][h][d][s].
template<int EPI, bool TRV>
__global__ __launch_bounds__(256, 3)
void gemm_ker(const ushort* __restrict__ A,
              const ushort* __restrict__ B0, const ushort* __restrict__ B1,
              const ushort* __restrict__ B2,
              const float* __restrict__ bias0, const float* __restrict__ bias1,
              const float* __restrict__ bias2,
              void* __restrict__ C0, void* __restrict__ C1, void* __restrict__ C2,
              int Kdim, int nblk)
{
  __shared__ ushort As[3][128 * 32];
  __shared__ ushort Bs[3][128 * 32];

  int id = blockIdx.y * gridDim.x + blockIdx.x;
  const int chunk = (gridDim.x * gridDim.y) >> 3;
  id = (id & 7) * chunk + (id >> 3);
  const int bm = id & 63;
  const int bnAll = id >> 6;
  const int sub = bnAll / nblk;
  const int bn = bnAll - sub * nblk;

  const ushort* Bw  = sub == 0 ? B0 : (sub == 1 ? B1 : B2);
  const float* bias = sub == 0 ? bias0 : (sub == 1 ? bias1 : bias2);
  const int Ndim = nblk * 128;

  const int tid = threadIdx.x;
  const int l = tid & 63, w = tid >> 6;
  const int wm = w >> 1, wn = w & 1;
  const int fr = l & 15, fg = l >> 4;

  const int srow_in = l >> 2;
  const int gks = ((l & 3) ^ ((l >> 3) & 3)) * 8;
  const ushort* Agl0 = A  + (size_t)(bm * 128 + w * 16 + srow_in) * Kdim + gks;
  const ushort* Agl1 = Agl0 + (size_t)64 * Kdim;
  const ushort* Bgl0 = Bw + (size_t)(bn * 128 + w * 16 + srow_in) * Kdim + gks;
  const ushort* Bgl1 = Bgl0 + (size_t)64 * Kdim;

  auto stage = [&](int b, int kt) {
    const int ko = kt * 32;
    ushort* al = &As[b][w * 64 * 8];
    ushort* bl = &Bs[b][w * 64 * 8];
    glds16(Agl0 + ko, al);
    glds16(Agl1 + ko, al + 256 * 8);
    glds16(Bgl0 + ko, bl);
    glds16(Bgl1 + ko, bl + 256 * 8);
  };

  const int se = (fg ^ ((fr >> 1) & 3)) * 8;

  f32x4 acc[4][4];
#pragma unroll
  for (int i = 0; i < 4; ++i)
#pragma unroll
    for (int j = 0; j < 4; ++j) acc[i][j] = f32x4{0.f, 0.f, 0.f, 0.f};

  stage(0, 0);
  stage(1, 1);
  asm volatile("s_waitcnt vmcnt(4)" ::: "memory");
  asm volatile("s_barrier" ::: "memory");

  const int nk = Kdim >> 5;
  for (int kt = 0; kt < nk; ++kt) {
    const int rb = kt % 3;
    if (kt + 2 < nk) stage((kt + 2) % 3, kt + 2);

    bf16x8 af[4], bfv[4];
#pragma unroll
    for (int i = 0; i < 4; ++i)
      af[i]  = *(const bf16x8*)&As[rb][(wm * 64 + i * 16 + fr) * 32 + se];
#pragma unroll
    for (int j = 0; j < 4; ++j)
      bfv[j] = *(const bf16x8*)&Bs[rb][(wn * 64 + j * 16 + fr) * 32 + se];

    __builtin_amdgcn_s_setprio(1);
#pragma unroll
    for (int i = 0; i < 4; ++i)
#pragma unroll
      for (int j = 0; j < 4; ++j)
        acc[i][j] = __builtin_amdgcn_mfma_f32_16x16x32_bf16(bfv[j], af[i], acc[i][j], 0, 0, 0);
    __builtin_amdgcn_s_setprio(0);

    if (kt + 1 < nk) {
      if (kt + 2 < nk) { asm volatile("s_waitcnt vmcnt(4)" ::: "memory"); }
      else             { asm volatile("s_waitcnt vmcnt(0)" ::: "memory"); }
      asm volatile("s_barrier" ::: "memory");
    }
  }

#pragma unroll
  for (int i = 0; i < 4; ++i) {
    const int row_g = bm * 128 + wm * 64 + i * 16 + fr;
#pragma unroll
    for (int j = 0; j < 4; ++j) {
      const int col = bn * 128 + wn * 64 + j * 16 + fg * 4;
      const float4 bv4 = *(const float4*)&bias[col];
      const float v0 = acc[i][j][0] + bv4.x;
      const float v1 = acc[i][j][1] + bv4.y;
      const float v2 = acc[i][j][2] + bv4.z;
      const float v3 = acc[i][j][3] + bv4.w;
      if (TRV && sub == 2) {
        const int b_ = row_g >> 9, s_ = row_g & 511;
        const int h_ = col >> 6, d0 = col & 63;
        ushort* vp = (ushort*)C2 + (((size_t)(b_ * HH + h_) * DHD + d0) * SS + s_);
        vp[0] = f2bf(v0); vp[SS] = f2bf(v1); vp[2 * SS] = f2bf(v2); vp[3 * SS] = f2bf(v3);
      } else if (EPI == 2) {
        ushort4 o4;
        o4.x = f2bf(gelu_t(v0)); o4.y = f2bf(gelu_t(v1));
        o4.z = f2bf(gelu_t(v2)); o4.w = f2bf(gelu_t(v3));
        *(ushort4*)&((ushort*)C0)[(size_t)row_g * Ndim + col] = o4;
      } else {
        void* Cout = sub == 0 ? C0 : (sub == 1 ? C1 : C2);
        ushort4 o4;
        o4.x = f2bf(v0); o4.y = f2bf(v1); o4.z = f2bf(v2); o4.w = f2bf(v3);
        *(ushort4*)&((ushort*)Cout)[(size_t)row_g * Ndim + col] = o4;
      }
    }
  }
}

// ================= split-K=2 GEMM for N=768 (O-proj, Wd) =================
// grid (64, 12): y encodes bn (6) x sk (2). f32 partials to P0/P1; bias in sk==0.
__global__ __launch_bounds__(256, 3)
void gemm_sk(const ushort* __restrict__ A, const ushort* __restrict__ Bw,
             const float* __restrict__ bias, float* __restrict__ P0,
             float* __restrict__ P1, int Kdim)
{
  __shared__ ushort As[3][128 * 32];
  __shared__ ushort Bs[3][128 * 32];

  int id = blockIdx.y * gridDim.x + blockIdx.x;
  const int chunk = (gridDim.x * gridDim.y) >> 3;   // 768/8 = 96
  id = (id & 7) * chunk + (id >> 3);
  const int bm = id & 63;
  const int rest = id >> 6;          // 0..11
  const int bn = rest >> 1;
  const int sk = rest & 1;

  const int Kh = Kdim >> 1;

  const int tid = threadIdx.x;
  const int l = tid & 63, w = tid >> 6;
  const int wm = w >> 1, wn = w & 1;
  const int fr = l & 15, fg = l >> 4;

  const int srow_in = l >> 2;
  const int gks = ((l & 3) ^ ((l >> 3) & 3)) * 8;
  const ushort* Agl0 = A  + (size_t)(bm * 128 + w * 16 + srow_in) * Kdim + sk * Kh + gks;
  const ushort* Agl1 = Agl0 + (size_t)64 * Kdim;
  const ushort* Bgl0 = Bw + (size_t)(bn * 128 + w * 16 + srow_in) * Kdim + sk * Kh + gks;
  const ushort* Bgl1 = Bgl0 + (size_t)64 * Kdim;

  auto stage = [&](int b, int kt) {
    const int ko = kt * 32;
    ushort* al = &As[b][w * 64 * 8];
    ushort* bl = &Bs[b][w * 64 * 8];
    glds16(Agl0 + ko, al);
    glds16(Agl1 + ko, al + 256 * 8);
    glds16(Bgl0 + ko, bl);
    glds16(Bgl1 + ko, bl + 256 * 8);
  };

  const int se = (fg ^ ((fr >> 1) & 3)) * 8;

  f32x4 acc[4][4];
#pragma unroll
  for (int i = 0; i < 4; ++i)
#pragma unroll
    for (int j = 0; j < 4; ++j) acc[i][j] = f32x4{0.f, 0.f, 0.f, 0.f};

  stage(0, 0);
  stage(1, 1);
  asm volatile("s_waitcnt vmcnt(4)" ::: "memory");
  asm volatile("s_barrier" ::: "memory");

  const int nk = Kh >> 5;
  for (int kt = 0; kt < nk; ++kt) {
    const int rb = kt % 3;
    if (kt + 2 < nk) stage((kt + 2) % 3, kt + 2);

    bf16x8 af[4], bfv[4];
#pragma unroll
    for (int i = 0; i < 4; ++i)
      af[i]  = *(const bf16x8*)&As[rb][(wm * 64 + i * 16 + fr) * 32 + se];
#pragma unroll
    for (int j = 0; j < 4; ++j)
      bfv[j] = *(const bf16x8*)&Bs[rb][(wn * 64 + j * 16 + fr) * 32 + se];

    __builtin_amdgcn_s_setprio(1);
#pragma unroll
    for (int i = 0; i < 4; ++i)
#pragma unroll
      for (int j = 0; j < 4; ++j)
        acc[i][j] = __builtin_amdgcn_mfma_f32_16x16x32_bf16(bfv[j], af[i], acc[i][j], 0, 0, 0);
    __builtin_amdgcn_s_setprio(0);

    if (kt + 1 < nk) {
      if (kt + 2 < nk) { asm volatile("s_waitcnt vmcnt(4)" ::: "memory"); }
      else             { asm volatile("s_waitcnt vmcnt(0)" ::: "memory"); }
      asm volatile("s_barrier" ::: "memory");
    }
  }

  float* P = sk ? P1 : P0;
  const float bs = sk ? 0.f : 1.f;
#pragma unroll
  for (int i = 0; i < 4; ++i) {
    const int row_g = bm * 128 + wm * 64 + i * 16 + fr;
#pragma unroll
    for (int j = 0; j < 4; ++j) {
      const int col = bn * 128 + wn * 64 + j * 16 + fg * 4;
      const float4 bv4 = *(const float4*)&bias[col];
      float4 o4;
      o4.x = acc[i][j][0] + bv4.x * bs;
      o4.y = acc[i][j][1] + bv4.y * bs;
      o4.z = acc[i][j][2] + bv4.z * bs;
      o4.w = acc[i][j][3] + bv4.w * bs;
      *(float4*)&P[(size_t)row_g * DD + col] = o4;
    }
  }
}

// ================= fused flash attention (V pre-transposed) =================
__global__ __launch_bounds__(256, 3)
void attn_kernel(const ushort* __restrict__ qb, const ushort* __restrict__ kb,
                 const ushort* __restrict__ vt, const float* __restrict__ relt,
                 const float* __restrict__ amask, ushort* __restrict__ ctxb)
{
  __shared__ ushort Kt[128][72];
  __shared__ ushort Vt[64][136];
  __shared__ ushort Pl[64][136];
  __shared__ float am_lds[512];
  __shared__ float rel_lds[1024];

  const int tid = threadIdx.x, lane = tid & 63, w = tid >> 6;

  int lin = blockIdx.y * gridDim.x + blockIdx.x;
  lin = (lin & 7) * 192 + (lin >> 3);
  const int qt = lin & 7;
  const int bh = lin >> 3;
  const int b = bh / HH, h = bh - b * HH;
  const int fr = lane & 15, fg = lane >> 4;

  for (int i = tid; i < 512; i += 256)
    am_lds[i] = (1.0f - amask[b * SS + i]) * -10000.0f;
  for (int i = tid; i < 1024; i += 256) {
    int d = i - 512;
    d = min(128, max(-128, d));
    rel_lds[i] = relt[(d + 128) * HH + h];
  }

  bf16x8 qf[2];
  {
    const int qrow = qt * 64 + w * 16 + fr;
    const ushort* p = qb + ((size_t)(b * SS + qrow) * DD) + h * DHD + fg * 8;
    qf[0] = *(const bf16x8*)p;
    qf[1] = *(const bf16x8*)(p + 32);
  }

  f32x4 o[4];
  float mrow[4], lrow[4];
#pragma unroll
  for (int r = 0; r < 4; ++r) { mrow[r] = -1e30f; lrow[r] = 0.f; }
#pragma unroll
  for (int d = 0; d < 4; ++d) o[d] = f32x4{0.f, 0.f, 0.f, 0.f};

  const int skr = tid >> 1;
  const int shd = (tid & 1) * 32;
  const int vrow = tid >> 2;
  const int vcg  = (tid & 3) * 32;
  const ushort* vgl = vt + ((size_t)bh * DHD + vrow) * SS + vcg;

  const int qg0 = qt * 64 + w * 16;

  for (int kt = 0; kt < 4; ++kt) {
    const size_t gbase = ((size_t)(b * SS + kt * 128 + skr) * DD) + h * DHD + shd;
    int4 kr0 = *(const int4*)(kb + gbase);
    int4 kr1 = *(const int4*)(kb + gbase + 8);
    int4 kr2 = *(const int4*)(kb + gbase + 16);
    int4 kr3 = *(const int4*)(kb + gbase + 24);
    const ushort* vp = vgl + kt * 128;
    int4 vr0 = *(const int4*)(vp);
    int4 vr1 = *(const int4*)(vp + 8);
    int4 vr2 = *(const int4*)(vp + 16);
    int4 vr3 = *(const int4*)(vp + 24);

    __syncthreads();
    *(int4*)&Kt[skr][shd]      = kr0;
    *(int4*)&Kt[skr][shd + 8]  = kr1;
    *(int4*)&Kt[skr][shd + 16] = kr2;
    *(int4*)&Kt[skr][shd + 24] = kr3;
    *(int4*)&Vt[vrow][vcg]      = vr0;
    *(int4*)&Vt[vrow][vcg + 8]  = vr1;
    *(int4*)&Vt[vrow][vcg + 16] = vr2;
    *(int4*)&Vt[vrow][vcg + 24] = vr3;
    __syncthreads();

    float sv[8][4];
    __builtin_amdgcn_s_setprio(1);
#pragma unroll
    for (int kc = 0; kc < 8; ++kc) {
      f32x4 s = f32x4{0.f, 0.f, 0.f, 0.f};
      bf16x8 kf0 = *(const bf16x8*)&Kt[kc * 16 + fr][fg * 8];
      bf16x8 kf1 = *(const bf16x8*)&Kt[kc * 16 + fr][32 + fg * 8];
      s = __builtin_amdgcn_mfma_f32_16x16x32_bf16(qf[0], kf0, s, 0, 0, 0);
      s = __builtin_amdgcn_mfma_f32_16x16x32_bf16(qf[1], kf1, s, 0, 0, 0);
      const int col = kt * 128 + kc * 16 + fr;
      const float am = am_lds[col];
      const int ridx = col - qg0 - fg * 4 + 512;
#pragma unroll
      for (int r = 0; r < 4; ++r)
        sv[kc][r] = s[r] * 0.125f + rel_lds[ridx - r] + am;
    }
    __builtin_amdgcn_s_setprio(0);

    float ef[4];
#pragma unroll
    for (int r = 0; r < 4; ++r) {
      float tmax = sv[0][r];
#pragma unroll
      for (int kc = 1; kc < 8; ++kc) tmax = fmaxf(tmax, sv[kc][r]);
#pragma unroll
      for (int off = 1; off < 16; off <<= 1) tmax = fmaxf(tmax, __shfl_xor(tmax, off));
      const float mnew = fmaxf(mrow[r], tmax);
      ef[r] = __expf(mrow[r] - mnew);
      float psum = 0.f;
      const int prow = w * 16 + fg * 4 + r;
#pragma unroll
      for (int kc = 0; kc < 8; ++kc) {
        float p = __expf(sv[kc][r] - mnew);
        psum += p;
        Pl[prow][kc * 16 + fr] = f2bf(p);
      }
#pragma unroll
      for (int off = 1; off < 16; off <<= 1) psum += __shfl_xor(psum, off);
      lrow[r] = lrow[r] * ef[r] + psum;
      mrow[r] = mnew;
    }
#pragma unroll
    for (int dc = 0; dc < 4; ++dc)
#pragma unroll
      for (int r = 0; r < 4; ++r) o[dc][r] *= ef[r];
    __syncthreads();

    __builtin_amdgcn_s_setprio(1);
#pragma unroll
    for (int dc = 0; dc < 4; ++dc)
#pragma unroll
      for (int ks = 0; ks < 4; ++ks) {
        bf16x8 pf = *(const bf16x8*)&Pl[w * 16 + fr][ks * 32 + fg * 8];
        bf16x8 vf = *(const bf16x8*)&Vt[dc * 16 + fr][ks * 32 + fg * 8];
        o[dc] = __builtin_amdgcn_mfma_f32_16x16x32_bf16(pf, vf, o[dc], 0, 0, 0);
      }
    __builtin_amdgcn_s_setprio(0);
  }

#pragma unroll
  for (int dc = 0; dc < 4; ++dc)
#pragma unroll
    for (int r = 0; r < 4; ++r) {
      const int qg = qt * 64 + w * 16 + fg * 4 + r;
      const float v = o[dc][r] / lrow[r];
      ctxb[((size_t)(b * SS + qg) * DD) + h * DHD + dc * 16 + fr] = f2bf(v);
    }
}

// ================= host launch =================
extern "C" void kernel_launch(void* const* d_in, const int* in_sizes, int n_in,
                              void* d_out, int out_size, void* d_ws, size_t ws_size,
                              hipStream_t stream) {
  const int*   ids   = (const int*)d_in[0];
  const float* amask = (const float*)d_in[1];
  const float* wemb  = (const float*)d_in[2];
  const float* pemb  = (const float*)d_in[3];
  const float* eln_w = (const float*)d_in[4];
  const float* eln_b = (const float*)d_in[5];
  const float* relt  = (const float*)d_in[6];
  const float* Wq    = (const float*)d_in[7];
  const float* bq    = (const float*)d_in[8];
  const float* Wk    = (const float*)d_in[9];
  const float* bk    = (const float*)d_in[10];
  const float* Wv    = (const float*)d_in[11];
  const float* bv    = (const float*)d_in[12];
  const float* Wo    = (const float*)d_in[13];
  const float* bo    = (const float*)d_in[14];
  const float* aln_w = (const float*)d_in[15];
  const float* aln_b = (const float*)d_in[16];
  const float* Wi    = (const float*)d_in[17];
  const float* bi    = (const float*)d_in[18];
  const float* Wd    = (const float*)d_in[19];
  const float* bd    = (const float*)d_in[20];
  const float* oln_w = (const float*)d_in[21];
  const float* oln_b = (const float*)d_in[22];

  size_t off = 0;
  auto carve = [&](size_t bytes) -> void* {
    void* r = (char*)d_ws + off;
    off += (bytes + 255) & ~(size_t)255;
    return r;
  };
  float*  hf     = (float*) carve((size_t)MM * DD * 4);
  ushort* hb     = (ushort*)carve((size_t)MM * DD * 2);
  ushort* qbuf   = (ushort*)carve((size_t)MM * DD * 2);
  ushort* kbuf   = (ushort*)carve((size_t)MM * DD * 2);
  ushort* vbuf   = (ushort*)carve((size_t)MM * DD * 2);   // vT[b][h][d][s]
  ushort* ctxb   = (ushort*)carve((size_t)MM * DD * 2);
  float*  gout   = (float*) carve((size_t)MM * DD * 4);   // split-K partial 0
  float*  gout2  = (float*) carve((size_t)MM * DD * 4);   // split-K partial 1
  ushort* interb = (ushort*)carve((size_t)MM * FF * 2);
  const int PD = DD * DD;
  const int PF = FF * DD;
  ushort* wBded  = (ushort*)carve((size_t)2 * PF * 2);    // Wi,Wd bf16 (dedicated)

  ushort* wA = interb;   // Wq,Wk,Wv,Wo bf16 in interb's dead window

  embed_ln_kernel<<<MM, 256, 0, stream>>>(ids, wemb, pemb, eln_w, eln_b, hf, hb);

  const dim3 gQKV(MM / 128, 3 * (DD / 128));  // 64 x 18
  const dim3 gSK(MM / 128, 2 * (DD / 128));   // 64 x 12 (split-K=2)
  const dim3 gF(MM / 128, FF / 128);          // 64 x 24
  const dim3 gA(SS / 64, BB * HH);            // 8 x 192
  const dim3 gC(PF / 1024, 6);                // 2304 x 6

  for (int l = 0; l < LL; ++l) {
    const size_t wo  = (size_t)l * PD;
    const size_t wio = (size_t)l * PF;

    convw6<<<gC, 256, 0, stream>>>(Wq + wo, Wk + wo, Wv + wo, Wo + wo,
                                   Wi + wio, Wd + wio, wA, wBded, PD, PF);

    gemm_ker<0, true><<<gQKV, 256, 0, stream>>>(hb, wA, wA + PD, wA + 2 * PD,
                                                bq + l * DD, bk + l * DD, bv + l * DD,
                                                qbuf, kbuf, vbuf, DD, DD / 128);

    attn_kernel<<<gA, 256, 0, stream>>>(qbuf, kbuf, vbuf, relt, amask, ctxb);

    gemm_sk<<<gSK, 256, 0, stream>>>(ctxb, wA + 3 * PD, bo + l * DD, gout, gout2, DD);
    add_ln2_kernel<<<MM, 256, 0, stream>>>(hf, gout, gout2,
                                           aln_w + l * DD, aln_b + l * DD, hf, hb);

    gemm_ker<2, false><<<gF, 256, 0, stream>>>(hb, wBded, wBded, wBded,
                                               bi + l * FF, bi + l * FF, bi + l * FF,
                                               interb, interb, interb, DD, FF / 128);
    gemm_sk<<<gSK, 256, 0, stream>>>(interb, wBded + PF, bd + l * DD, gout, gout2, FF);

    float* outp = (l == LL - 1) ? (float*)d_out : hf;
    add_ln2_kernel<<<MM, 256, 0, stream>>>(hf, gout, gout2,
                                           oln_w + l * DD, oln_b + l * DD, outp, hb);
  }
}

// Round 10
// 3600.101 us; speedup vs baseline: 1.1541x; 1.0089x over previous
//
#include <hip/hip_runtime.h>
#include <cstdint>
#include <cstddef>

// ---------------- config ----------------
#define BB 16
#define SS 512
#define DD 768
#define HH 12
#define FF 3072
#define LL 12
#define DHD 64
#define MM (BB*SS)   // 8192 rows

typedef __attribute__((ext_vector_type(8))) short bf16x8;
typedef __attribute__((ext_vector_type(4))) float f32x4;

__device__ __forceinline__ ushort f2bf(float f) {
  union { float f; uint32_t u; } x; x.f = f;
  uint32_t r = x.u + 0x7FFFu + ((x.u >> 16) & 1u);
  return (ushort)(r >> 16);
}

__device__ __forceinline__ void glds16(const ushort* g, ushort* l) {
  __builtin_amdgcn_global_load_lds((__attribute__((address_space(1))) void*)g,
                                   (__attribute__((address_space(3))) void*)l,
                                   16, 0, 0);
}

__device__ __forceinline__ float gelu_t(float v) {
  float y = 0.7978845608f * (v + 0.044715f * v * v * v);
  y = fminf(fmaxf(y, -15.f), 15.f);
  float e = __expf(2.f * y);
  return 0.5f * v * (2.f - 2.f / (e + 1.f));
}

// ================= weight f32 -> bf16 conversion (6 tensors, one dispatch) ==========
__global__ __launch_bounds__(256)
void convw6(const float* __restrict__ s0, const float* __restrict__ s1,
            const float* __restrict__ s2, const float* __restrict__ s3,
            const float* __restrict__ s4, const float* __restrict__ s5,
            ushort* __restrict__ dA, ushort* __restrict__ dB, int perD, int perF)
{
  const int y = blockIdx.y;
  const int per = (y < 4) ? perD : perF;
  const int i = (blockIdx.x * 256 + threadIdx.x) * 4;
  if (i >= per) return;
  const float* s = y == 0 ? s0 : y == 1 ? s1 : y == 2 ? s2 : y == 3 ? s3 : y == 4 ? s4 : s5;
  ushort* dst = (y < 4) ? (dA + (size_t)y * perD) : (dB + (size_t)(y - 4) * perF);
  const float4 v = *(const float4*)(s + i);
  ushort4 o;
  o.x = f2bf(v.x); o.y = f2bf(v.y); o.z = f2bf(v.z); o.w = f2bf(v.w);
  *(ushort4*)(dst + i) = o;
}

// ================= embedding + LayerNorm =================
__global__ __launch_bounds__(256)
void embed_ln_kernel(const int* __restrict__ ids, const float* __restrict__ wemb,
                     const float* __restrict__ pemb, const float* __restrict__ g,
                     const float* __restrict__ bt, float* __restrict__ hf,
                     ushort* __restrict__ hb)
{
  const int row = blockIdx.x;
  const int s = row & (SS - 1);
  const int id = ids[row];
  const float* wp = wemb + (size_t)id * DD;
  const float* pp = pemb + (size_t)s * DD;
  const int tid = threadIdx.x;
  float v[3]; float sum = 0.f, sq = 0.f;
#pragma unroll
  for (int j = 0; j < 3; ++j) {
    int e = tid + j * 256;
    v[j] = wp[e] + pp[e];
    sum += v[j]; sq += v[j] * v[j];
  }
  __shared__ float red[2][4];
#pragma unroll
  for (int off = 32; off >= 1; off >>= 1) { sum += __shfl_xor(sum, off); sq += __shfl_xor(sq, off); }
  const int lane = tid & 63, wid = tid >> 6;
  if (lane == 0) { red[0][wid] = sum; red[1][wid] = sq; }
  __syncthreads();
  sum = red[0][0] + red[0][1] + red[0][2] + red[0][3];
  sq  = red[1][0] + red[1][1] + red[1][2] + red[1][3];
  const float mean = sum * (1.f / DD);
  const float var  = sq  * (1.f / DD) - mean * mean;
  const float rstd = rsqrtf(var + 1e-12f);
  const size_t base = (size_t)row * DD;
#pragma unroll
  for (int j = 0; j < 3; ++j) {
    int e = tid + j * 256;
    float o = (v[j] - mean) * rstd * g[e] + bt[e];
    hf[base + e] = o;
    hb[base + e] = f2bf(o);
  }
}

// ================= residual + two split-K partials + LayerNorm =================
__global__ __launch_bounds__(256)
void add_ln2_kernel(const float* __restrict__ res, const float* __restrict__ p0,
                    const float* __restrict__ p1, const float* __restrict__ g,
                    const float* __restrict__ bt, float* __restrict__ hf,
                    ushort* __restrict__ hb)
{
  const int row = blockIdx.x;
  const int tid = threadIdx.x;
  const size_t base = (size_t)row * DD;
  float v[3]; float sum = 0.f, sq = 0.f;
#pragma unroll
  for (int j = 0; j < 3; ++j) {
    int e = tid + j * 256;
    v[j] = res[base + e] + p0[base + e] + p1[base + e];
    sum += v[j]; sq += v[j] * v[j];
  }
  __shared__ float red[2][4];
#pragma unroll
  for (int off = 32; off >= 1; off >>= 1) { sum += __shfl_xor(sum, off); sq += __shfl_xor(sq, off); }
  const int lane = tid & 63, wid = tid >> 6;
  if (lane == 0) { red[0][wid] = sum; red[1][wid] = sq; }
  __syncthreads();
  sum = red[0][0] + red[0][1] + red[0][2] + red[0][3];
  sq  = red[1][0] + red[1][1] + red[1][2] + red[1][3];
  const float mean = sum * (1.f / DD);
  const float var  = sq  * (1.f / DD) - mean * mean;
  const float rstd = rsqrtf(var + 1e-12f);
#pragma unroll
  for (int j = 0; j < 3; ++j) {
    int e = tid + j * 256;
    float o = (v[j] - mean) * rstd * g[e] + bt[e];
    hf[base + e] = o;
    hb[base + e] = f2bf(o);
  }
}

// ================= GEMM: C[M,N] = A[M,K](bf16) @ Bw[N,K](bf16)^T + bias =================
// m97 schedule: 128x128 tile, BK=32, DOUBLE-buffered (32KB LDS -> 4 blocks/CU),
// stage -> ds_read -> MFMA -> __syncthreads (vmcnt0 drain IS the dbuf requirement).
// XOR-swizzled staging (0 bank conflicts), swapped-operand MFMA, vectorized epilogue.
// EPI 0: bf16 out; 2: bf16 out + gelu. TRV: sub==2 writes vT[b][h][d][s].
template<int EPI, bool TRV>
__global__ __launch_bounds__(256, 4)
void gemm_ker(const ushort* __restrict__ A,
              const ushort* __restrict__ B0, const ushort* __restrict__ B1,
              const ushort* __restrict__ B2,
              const float* __restrict__ bias0, const float* __restrict__ bias1,
              const float* __restrict__ bias2,
              void* __restrict__ C0, void* __restrict__ C1, void* __restrict__ C2,
              int Kdim, int nblk)
{
  __shared__ ushort As[2][128 * 32];
  __shared__ ushort Bs[2][128 * 32];

  int id = blockIdx.y * gridDim.x + blockIdx.x;
  const int chunk = (gridDim.x * gridDim.y) >> 3;
  id = (id & 7) * chunk + (id >> 3);
  const int bm = id & 63;
  const int bnAll = id >> 6;
  const int sub = bnAll / nblk;
  const int bn = bnAll - sub * nblk;

  const ushort* Bw  = sub == 0 ? B0 : (sub == 1 ? B1 : B2);
  const float* bias = sub == 0 ? bias0 : (sub == 1 ? bias1 : bias2);
  const int Ndim = nblk * 128;

  const int tid = threadIdx.x;
  const int l = tid & 63, w = tid >> 6;
  const int wm = w >> 1, wn = w & 1;
  const int fr = l & 15, fg = l >> 4;

  const int srow_in = l >> 2;
  const int gks = ((l & 3) ^ ((l >> 3) & 3)) * 8;
  const ushort* Agl0 = A  + (size_t)(bm * 128 + w * 16 + srow_in) * Kdim + gks;
  const ushort* Agl1 = Agl0 + (size_t)64 * Kdim;
  const ushort* Bgl0 = Bw + (size_t)(bn * 128 + w * 16 + srow_in) * Kdim + gks;
  const ushort* Bgl1 = Bgl0 + (size_t)64 * Kdim;

  auto stage = [&](int b, int kt) {
    const int ko = kt * 32;
    ushort* al = &As[b][w * 64 * 8];
    ushort* bl = &Bs[b][w * 64 * 8];
    glds16(Agl0 + ko, al);
    glds16(Agl1 + ko, al + 256 * 8);
    glds16(Bgl0 + ko, bl);
    glds16(Bgl1 + ko, bl + 256 * 8);
  };

  const int se = (fg ^ ((fr >> 1) & 3)) * 8;

  f32x4 acc[4][4];
#pragma unroll
  for (int i = 0; i < 4; ++i)
#pragma unroll
    for (int j = 0; j < 4; ++j) acc[i][j] = f32x4{0.f, 0.f, 0.f, 0.f};

  stage(0, 0);
  __syncthreads();

  const int nk = Kdim >> 5;
  int cur = 0;
  for (int kt = 0; kt < nk; ++kt) {
    if (kt + 1 < nk) stage(cur ^ 1, kt + 1);

    bf16x8 af[4], bfv[4];
#pragma unroll
    for (int i = 0; i < 4; ++i)
      af[i]  = *(const bf16x8*)&As[cur][(wm * 64 + i * 16 + fr) * 32 + se];
#pragma unroll
    for (int j = 0; j < 4; ++j)
      bfv[j] = *(const bf16x8*)&Bs[cur][(wn * 64 + j * 16 + fr) * 32 + se];

    __builtin_amdgcn_s_setprio(1);
#pragma unroll
    for (int i = 0; i < 4; ++i)
#pragma unroll
      for (int j = 0; j < 4; ++j)
        acc[i][j] = __builtin_amdgcn_mfma_f32_16x16x32_bf16(bfv[j], af[i], acc[i][j], 0, 0, 0);
    __builtin_amdgcn_s_setprio(0);

    __syncthreads();
    cur ^= 1;
  }

#pragma unroll
  for (int i = 0; i < 4; ++i) {
    const int row_g = bm * 128 + wm * 64 + i * 16 + fr;
#pragma unroll
    for (int j = 0; j < 4; ++j) {
      const int col = bn * 128 + wn * 64 + j * 16 + fg * 4;
      const float4 bv4 = *(const float4*)&bias[col];
      const float v0 = acc[i][j][0] + bv4.x;
      const float v1 = acc[i][j][1] + bv4.y;
      const float v2 = acc[i][j][2] + bv4.z;
      const float v3 = acc[i][j][3] + bv4.w;
      if (TRV && sub == 2) {
        const int b_ = row_g >> 9, s_ = row_g & 511;
        const int h_ = col >> 6, d0 = col & 63;
        ushort* vp = (ushort*)C2 + (((size_t)(b_ * HH + h_) * DHD + d0) * SS + s_);
        vp[0] = f2bf(v0); vp[SS] = f2bf(v1); vp[2 * SS] = f2bf(v2); vp[3 * SS] = f2bf(v3);
      } else if (EPI == 2) {
        ushort4 o4;
        o4.x = f2bf(gelu_t(v0)); o4.y = f2bf(gelu_t(v1));
        o4.z = f2bf(gelu_t(v2)); o4.w = f2bf(gelu_t(v3));
        *(ushort4*)&((ushort*)C0)[(size_t)row_g * Ndim + col] = o4;
      } else {
        void* Cout = sub == 0 ? C0 : (sub == 1 ? C1 : C2);
        ushort4 o4;
        o4.x = f2bf(v0); o4.y = f2bf(v1); o4.z = f2bf(v2); o4.w = f2bf(v3);
        *(ushort4*)&((ushort*)Cout)[(size_t)row_g * Ndim + col] = o4;
      }
    }
  }
}

// ================= split-K=2 GEMM for N=768 (O-proj, Wd) =================
// grid (64, 12): y encodes bn (6) x sk (2). f32 partials to P0/P1; bias in sk==0.
__global__ __launch_bounds__(256, 4)
void gemm_sk(const ushort* __restrict__ A, const ushort* __restrict__ Bw,
             const float* __restrict__ bias, float* __restrict__ P0,
             float* __restrict__ P1, int Kdim)
{
  __shared__ ushort As[2][128 * 32];
  __shared__ ushort Bs[2][128 * 32];

  int id = blockIdx.y * gridDim.x + blockIdx.x;
  const int chunk = (gridDim.x * gridDim.y) >> 3;
  id = (id & 7) * chunk + (id >> 3);
  const int bm = id & 63;
  const int rest = id >> 6;
  const int bn = rest >> 1;
  const int sk = rest & 1;

  const int Kh = Kdim >> 1;

  const int tid = threadIdx.x;
  const int l = tid & 63, w = tid >> 6;
  const int wm = w >> 1, wn = w & 1;
  const int fr = l & 15, fg = l >> 4;

  const int srow_in = l >> 2;
  const int gks = ((l & 3) ^ ((l >> 3) & 3)) * 8;
  const ushort* Agl0 = A  + (size_t)(bm * 128 + w * 16 + srow_in) * Kdim + sk * Kh + gks;
  const ushort* Agl1 = Agl0 + (size_t)64 * Kdim;
  const ushort* Bgl0 = Bw + (size_t)(bn * 128 + w * 16 + srow_in) * Kdim + sk * Kh + gks;
  const ushort* Bgl1 = Bgl0 + (size_t)64 * Kdim;

  auto stage = [&](int b, int kt) {
    const int ko = kt * 32;
    ushort* al = &As[b][w * 64 * 8];
    ushort* bl = &Bs[b][w * 64 * 8];
    glds16(Agl0 + ko, al);
    glds16(Agl1 + ko, al + 256 * 8);
    glds16(Bgl0 + ko, bl);
    glds16(Bgl1 + ko, bl + 256 * 8);
  };

  const int se = (fg ^ ((fr >> 1) & 3)) * 8;

  f32x4 acc[4][4];
#pragma unroll
  for (int i = 0; i < 4; ++i)
#pragma unroll
    for (int j = 0; j < 4; ++j) acc[i][j] = f32x4{0.f, 0.f, 0.f, 0.f};

  stage(0, 0);
  __syncthreads();

  const int nk = Kh >> 5;
  int cur = 0;
  for (int kt = 0; kt < nk; ++kt) {
    if (kt + 1 < nk) stage(cur ^ 1, kt + 1);

    bf16x8 af[4], bfv[4];
#pragma unroll
    for (int i = 0; i < 4; ++i)
      af[i]  = *(const bf16x8*)&As[cur][(wm * 64 + i * 16 + fr) * 32 + se];
#pragma unroll
    for (int j = 0; j < 4; ++j)
      bfv[j] = *(const bf16x8*)&Bs[cur][(wn * 64 + j * 16 + fr) * 32 + se];

    __builtin_amdgcn_s_setprio(1);
#pragma unroll
    for (int i = 0; i < 4; ++i)
#pragma unroll
      for (int j = 0; j < 4; ++j)
        acc[i][j] = __builtin_amdgcn_mfma_f32_16x16x32_bf16(bfv[j], af[i], acc[i][j], 0, 0, 0);
    __builtin_amdgcn_s_setprio(0);

    __syncthreads();
    cur ^= 1;
  }

  float* P = sk ? P1 : P0;
  const float bs = sk ? 0.f : 1.f;
#pragma unroll
  for (int i = 0; i < 4; ++i) {
    const int row_g = bm * 128 + wm * 64 + i * 16 + fr;
#pragma unroll
    for (int j = 0; j < 4; ++j) {
      const int col = bn * 128 + wn * 64 + j * 16 + fg * 4;
      const float4 bv4 = *(const float4*)&bias[col];
      float4 o4;
      o4.x = acc[i][j][0] + bv4.x * bs;
      o4.y = acc[i][j][1] + bv4.y * bs;
      o4.z = acc[i][j][2] + bv4.z * bs;
      o4.w = acc[i][j][3] + bv4.w * bs;
      *(float4*)&P[(size_t)row_g * DD + col] = o4;
    }
  }
}

// ================= fused flash attention (V pre-transposed) =================
__global__ __launch_bounds__(256, 3)
void attn_kernel(const ushort* __restrict__ qb, const ushort* __restrict__ kb,
                 const ushort* __restrict__ vt, const float* __restrict__ relt,
                 const float* __restrict__ amask, ushort* __restrict__ ctxb)
{
  __shared__ ushort Kt[128][72];
  __shared__ ushort Vt[64][136];
  __shared__ ushort Pl[64][136];
  __shared__ float am_lds[512];
  __shared__ float rel_lds[1024];

  const int tid = threadIdx.x, lane = tid & 63, w = tid >> 6;

  int lin = blockIdx.y * gridDim.x + blockIdx.x;
  lin = (lin & 7) * 192 + (lin >> 3);
  const int qt = lin & 7;
  const int bh = lin >> 3;
  const int b = bh / HH, h = bh - b * HH;
  const int fr = lane & 15, fg = lane >> 4;

  for (int i = tid; i < 512; i += 256)
    am_lds[i] = (1.0f - amask[b * SS + i]) * -10000.0f;
  for (int i = tid; i < 1024; i += 256) {
    int d = i - 512;
    d = min(128, max(-128, d));
    rel_lds[i] = relt[(d + 128) * HH + h];
  }

  bf16x8 qf[2];
  {
    const int qrow = qt * 64 + w * 16 + fr;
    const ushort* p = qb + ((size_t)(b * SS + qrow) * DD) + h * DHD + fg * 8;
    qf[0] = *(const bf16x8*)p;
    qf[1] = *(const bf16x8*)(p + 32);
  }

  f32x4 o[4];
  float mrow[4], lrow[4];
#pragma unroll
  for (int r = 0; r < 4; ++r) { mrow[r] = -1e30f; lrow[r] = 0.f; }
#pragma unroll
  for (int d = 0; d < 4; ++d) o[d] = f32x4{0.f, 0.f, 0.f, 0.f};

  const int skr = tid >> 1;
  const int shd = (tid & 1) * 32;
  const int vrow = tid >> 2;
  const int vcg  = (tid & 3) * 32;
  const ushort* vgl = vt + ((size_t)bh * DHD + vrow) * SS + vcg;

  const int qg0 = qt * 64 + w * 16;

  for (int kt = 0; kt < 4; ++kt) {
    const size_t gbase = ((size_t)(b * SS + kt * 128 + skr) * DD) + h * DHD + shd;
    int4 kr0 = *(const int4*)(kb + gbase);
    int4 kr1 = *(const int4*)(kb + gbase + 8);
    int4 kr2 = *(const int4*)(kb + gbase + 16);
    int4 kr3 = *(const int4*)(kb + gbase + 24);
    const ushort* vp = vgl + kt * 128;
    int4 vr0 = *(const int4*)(vp);
    int4 vr1 = *(const int4*)(vp + 8);
    int4 vr2 = *(const int4*)(vp + 16);
    int4 vr3 = *(const int4*)(vp + 24);

    __syncthreads();
    *(int4*)&Kt[skr][shd]      = kr0;
    *(int4*)&Kt[skr][shd + 8]  = kr1;
    *(int4*)&Kt[skr][shd + 16] = kr2;
    *(int4*)&Kt[skr][shd + 24] = kr3;
    *(int4*)&Vt[vrow][vcg]      = vr0;
    *(int4*)&Vt[vrow][vcg + 8]  = vr1;
    *(int4*)&Vt[vrow][vcg + 16] = vr2;
    *(int4*)&Vt[vrow][vcg + 24] = vr3;
    __syncthreads();

    float sv[8][4];
    __builtin_amdgcn_s_setprio(1);
#pragma unroll
    for (int kc = 0; kc < 8; ++kc) {
      f32x4 s = f32x4{0.f, 0.f, 0.f, 0.f};
      bf16x8 kf0 = *(const bf16x8*)&Kt[kc * 16 + fr][fg * 8];
      bf16x8 kf1 = *(const bf16x8*)&Kt[kc * 16 + fr][32 + fg * 8];
      s = __builtin_amdgcn_mfma_f32_16x16x32_bf16(qf[0], kf0, s, 0, 0, 0);
      s = __builtin_amdgcn_mfma_f32_16x16x32_bf16(qf[1], kf1, s, 0, 0, 0);
      const int col = kt * 128 + kc * 16 + fr;
      const float am = am_lds[col];
      const int ridx = col - qg0 - fg * 4 + 512;
#pragma unroll
      for (int r = 0; r < 4; ++r)
        sv[kc][r] = s[r] * 0.125f + rel_lds[ridx - r] + am;
    }
    __builtin_amdgcn_s_setprio(0);

    float ef[4];
#pragma unroll
    for (int r = 0; r < 4; ++r) {
      float tmax = sv[0][r];
#pragma unroll
      for (int kc = 1; kc < 8; ++kc) tmax = fmaxf(tmax, sv[kc][r]);
#pragma unroll
      for (int off = 1; off < 16; off <<= 1) tmax = fmaxf(tmax, __shfl_xor(tmax, off));
      const float mnew = fmaxf(mrow[r], tmax);
      ef[r] = __expf(mrow[r] - mnew);
      float psum = 0.f;
      const int prow = w * 16 + fg * 4 + r;
#pragma unroll
      for (int kc = 0; kc < 8; ++kc) {
        float p = __expf(sv[kc][r] - mnew);
        psum += p;
        Pl[prow][kc * 16 + fr] = f2bf(p);
      }
#pragma unroll
      for (int off = 1; off < 16; off <<= 1) psum += __shfl_xor(psum, off);
      lrow[r] = lrow[r] * ef[r] + psum;
      mrow[r] = mnew;
    }
#pragma unroll
    for (int dc = 0; dc < 4; ++dc)
#pragma unroll
      for (int r = 0; r < 4; ++r) o[dc][r] *= ef[r];
    __syncthreads();

    __builtin_amdgcn_s_setprio(1);
#pragma unroll
    for (int dc = 0; dc < 4; ++dc)
#pragma unroll
      for (int ks = 0; ks < 4; ++ks) {
        bf16x8 pf = *(const bf16x8*)&Pl[w * 16 + fr][ks * 32 + fg * 8];
        bf16x8 vf = *(const bf16x8*)&Vt[dc * 16 + fr][ks * 32 + fg * 8];
        o[dc] = __builtin_amdgcn_mfma_f32_16x16x32_bf16(pf, vf, o[dc], 0, 0, 0);
      }
    __builtin_amdgcn_s_setprio(0);
  }

#pragma unroll
  for (int dc = 0; dc < 4; ++dc)
#pragma unroll
    for (int r = 0; r < 4; ++r) {
      const int qg = qt * 64 + w * 16 + fg * 4 + r;
      const float v = o[dc][r] / lrow[r];
      ctxb[((size_t)(b * SS + qg) * DD) + h * DHD + dc * 16 + fr] = f2bf(v);
    }
}

// ================= host launch =================
extern "C" void kernel_launch(void* const* d_in, const int* in_sizes, int n_in,
                              void* d_out, int out_size, void* d_ws, size_t ws_size,
                              hipStream_t stream) {
  const int*   ids   = (const int*)d_in[0];
  const float* amask = (const float*)d_in[1];
  const float* wemb  = (const float*)d_in[2];
  const float* pemb  = (const float*)d_in[3];
  const float* eln_w = (const float*)d_in[4];
  const float* eln_b = (const float*)d_in[5];
  const float* relt  = (const float*)d_in[6];
  const float* Wq    = (const float*)d_in[7];
  const float* bq    = (const float*)d_in[8];
  const float* Wk    = (const float*)d_in[9];
  const float* bk    = (const float*)d_in[10];
  const float* Wv    = (const float*)d_in[11];
  const float* bv    = (const float*)d_in[12];
  const float* Wo    = (const float*)d_in[13];
  const float* bo    = (const float*)d_in[14];
  const float* aln_w = (const float*)d_in[15];
  const float* aln_b = (const float*)d_in[16];
  const float* Wi    = (const float*)d_in[17];
  const float* bi    = (const float*)d_in[18];
  const float* Wd    = (const float*)d_in[19];
  const float* bd    = (const float*)d_in[20];
  const float* oln_w = (const float*)d_in[21];
  const float* oln_b = (const float*)d_in[22];

  size_t off = 0;
  auto carve = [&](size_t bytes) -> void* {
    void* r = (char*)d_ws + off;
    off += (bytes + 255) & ~(size_t)255;
    return r;
  };
  float*  hf     = (float*) carve((size_t)MM * DD * 4);
  ushort* hb     = (ushort*)carve((size_t)MM * DD * 2);
  ushort* qbuf   = (ushort*)carve((size_t)MM * DD * 2);
  ushort* kbuf   = (ushort*)carve((size_t)MM * DD * 2);
  ushort* vbuf   = (ushort*)carve((size_t)MM * DD * 2);   // vT[b][h][d][s]
  ushort* ctxb   = (ushort*)carve((size_t)MM * DD * 2);
  float*  gout   = (float*) carve((size_t)MM * DD * 4);   // split-K partial 0
  float*  gout2  = (float*) carve((size_t)MM * DD * 4);   // split-K partial 1
  ushort* interb = (ushort*)carve((size_t)MM * FF * 2);
  const int PD = DD * DD;
  const int PF = FF * DD;
  ushort* wBded  = (ushort*)carve((size_t)2 * PF * 2);    // Wi,Wd bf16 (dedicated)

  ushort* wA = interb;   // Wq,Wk,Wv,Wo bf16 in interb's dead window

  embed_ln_kernel<<<MM, 256, 0, stream>>>(ids, wemb, pemb, eln_w, eln_b, hf, hb);

  const dim3 gQKV(MM / 128, 3 * (DD / 128));  // 64 x 18
  const dim3 gSK(MM / 128, 2 * (DD / 128));   // 64 x 12 (split-K=2)
  const dim3 gF(MM / 128, FF / 128);          // 64 x 24
  const dim3 gA(SS / 64, BB * HH);            // 8 x 192
  const dim3 gC(PF / 1024, 6);                // 2304 x 6

  for (int l = 0; l < LL; ++l) {
    const size_t wo  = (size_t)l * PD;
    const size_t wio = (size_t)l * PF;

    convw6<<<gC, 256, 0, stream>>>(Wq + wo, Wk + wo, Wv + wo, Wo + wo,
                                   Wi + wio, Wd + wio, wA, wBded, PD, PF);

    gemm_ker<0, true><<<gQKV, 256, 0, stream>>>(hb, wA, wA + PD, wA + 2 * PD,
                                                bq + l * DD, bk + l * DD, bv + l * DD,
                                                qbuf, kbuf, vbuf, DD, DD / 128);

    attn_kernel<<<gA, 256, 0, stream>>>(qbuf, kbuf, vbuf, relt, amask, ctxb);

    gemm_sk<<<gSK, 256, 0, stream>>>(ctxb, wA + 3 * PD, bo + l * DD, gout, gout2, DD);
    add_ln2_kernel<<<MM, 256, 0, stream>>>(hf, gout, gout2,
                                           aln_w + l * DD, aln_b + l * DD, hf, hb);

    gemm_ker<2, false><<<gF, 256, 0, stream>>>(hb, wBded, wBded, wBded,
                                               bi + l * FF, bi + l * FF, bi + l * FF,
                                               interb, interb, interb, DD, FF / 128);
    gemm_sk<<<gSK, 256, 0, stream>>>(interb, wBded + PF, bd + l * DD, gout, gout2, FF);

    float* outp = (l == LL - 1) ? (float*)d_out : hf;
    add_ln2_kernel<<<MM, 256, 0, stream>>>(hf, gout, gout2,
                                           oln_w + l * DD, oln_b + l * DD, outp, hb);
  }
}

// Round 11
// 3354.506 us; speedup vs baseline: 1.2386x; 1.0732x over previous
//
#include <hip/hip_runtime.h>
#include <cstdint>
#include <cstddef>

// ---------------- config ----------------
#define BB 16
#define SS 512
#define DD 768
#define HH 12
#define FF 3072
#define LL 12
#define DHD 64
#define MM (BB*SS)   // 8192 rows

typedef __attribute__((ext_vector_type(8))) short bf16x8;
typedef __attribute__((ext_vector_type(4))) float f32x4;

__device__ __forceinline__ ushort f2bf(float f) {
  union { float f; uint32_t u; } x; x.f = f;
  uint32_t r = x.u + 0x7FFFu + ((x.u >> 16) & 1u);
  return (ushort)(r >> 16);
}
__device__ __forceinline__ float bf2f(ushort u) {
  union { uint32_t u; float f; } x; x.u = (uint32_t)u << 16;
  return x.f;
}

__device__ __forceinline__ void glds16(const ushort* g, ushort* l) {
  __builtin_amdgcn_global_load_lds((__attribute__((address_space(1))) void*)g,
                                   (__attribute__((address_space(3))) void*)l,
                                   16, 0, 0);
}

__device__ __forceinline__ float gelu_t(float v) {
  // v * sigmoid(2y), y = 0.79788456(v + 0.044715 v^3); == tanh-gelu, 8 VALU ops
  const float v2 = v * v;
  const float u = v * (-1.5957691216f - 0.0713548163f * v2);   // -2y
  return v / (1.f + __expf(u));
}

// ================= weight f32 -> bf16 conversion (6 tensors, one dispatch) ==========
__global__ __launch_bounds__(256)
void convw6(const float* __restrict__ s0, const float* __restrict__ s1,
            const float* __restrict__ s2, const float* __restrict__ s3,
            const float* __restrict__ s4, const float* __restrict__ s5,
            ushort* __restrict__ dA, ushort* __restrict__ dB, int perD, int perF)
{
  const int y = blockIdx.y;
  const int per = (y < 4) ? perD : perF;
  const int i = (blockIdx.x * 256 + threadIdx.x) * 4;
  if (i >= per) return;
  const float* s = y == 0 ? s0 : y == 1 ? s1 : y == 2 ? s2 : y == 3 ? s3 : y == 4 ? s4 : s5;
  ushort* dst = (y < 4) ? (dA + (size_t)y * perD) : (dB + (size_t)(y - 4) * perF);
  const float4 v = *(const float4*)(s + i);
  ushort4 o;
  o.x = f2bf(v.x); o.y = f2bf(v.y); o.z = f2bf(v.z); o.w = f2bf(v.w);
  *(ushort4*)(dst + i) = o;
}

// ================= embedding + LayerNorm =================
__global__ __launch_bounds__(256)
void embed_ln_kernel(const int* __restrict__ ids, const float* __restrict__ wemb,
                     const float* __restrict__ pemb, const float* __restrict__ g,
                     const float* __restrict__ bt, float* __restrict__ hf,
                     ushort* __restrict__ hb)
{
  const int row = blockIdx.x;
  const int s = row & (SS - 1);
  const int id = ids[row];
  const float* wp = wemb + (size_t)id * DD;
  const float* pp = pemb + (size_t)s * DD;
  const int tid = threadIdx.x;
  float v[3]; float sum = 0.f, sq = 0.f;
#pragma unroll
  for (int j = 0; j < 3; ++j) {
    int e = tid + j * 256;
    v[j] = wp[e] + pp[e];
    sum += v[j]; sq += v[j] * v[j];
  }
  __shared__ float red[2][4];
#pragma unroll
  for (int off = 32; off >= 1; off >>= 1) { sum += __shfl_xor(sum, off); sq += __shfl_xor(sq, off); }
  const int lane = tid & 63, wid = tid >> 6;
  if (lane == 0) { red[0][wid] = sum; red[1][wid] = sq; }
  __syncthreads();
  sum = red[0][0] + red[0][1] + red[0][2] + red[0][3];
  sq  = red[1][0] + red[1][1] + red[1][2] + red[1][3];
  const float mean = sum * (1.f / DD);
  const float var  = sq  * (1.f / DD) - mean * mean;
  const float rstd = rsqrtf(var + 1e-12f);
  const size_t base = (size_t)row * DD;
#pragma unroll
  for (int j = 0; j < 3; ++j) {
    int e = tid + j * 256;
    float o = (v[j] - mean) * rstd * g[e] + bt[e];
    hf[base + e] = o;
    hb[base + e] = f2bf(o);
  }
}

// ================= residual + two bf16 split-K partials + LayerNorm =================
__global__ __launch_bounds__(256)
void add_ln2_kernel(const float* __restrict__ res, const ushort* __restrict__ p0,
                    const ushort* __restrict__ p1, const float* __restrict__ g,
                    const float* __restrict__ bt, float* __restrict__ hf,
                    ushort* __restrict__ hb)
{
  const int row = blockIdx.x;
  const int tid = threadIdx.x;
  const size_t base = (size_t)row * DD;
  float v[3]; float sum = 0.f, sq = 0.f;
#pragma unroll
  for (int j = 0; j < 3; ++j) {
    int e = tid + j * 256;
    v[j] = res[base + e] + bf2f(p0[base + e]) + bf2f(p1[base + e]);
    sum += v[j]; sq += v[j] * v[j];
  }
  __shared__ float red[2][4];
#pragma unroll
  for (int off = 32; off >= 1; off >>= 1) { sum += __shfl_xor(sum, off); sq += __shfl_xor(sq, off); }
  const int lane = tid & 63, wid = tid >> 6;
  if (lane == 0) { red[0][wid] = sum; red[1][wid] = sq; }
  __syncthreads();
  sum = red[0][0] + red[0][1] + red[0][2] + red[0][3];
  sq  = red[1][0] + red[1][1] + red[1][2] + red[1][3];
  const float mean = sum * (1.f / DD);
  const float var  = sq  * (1.f / DD) - mean * mean;
  const float rstd = rsqrtf(var + 1e-12f);
#pragma unroll
  for (int j = 0; j < 3; ++j) {
    int e = tid + j * 256;
    float o = (v[j] - mean) * rstd * g[e] + bt[e];
    hf[base + e] = o;
    hb[base + e] = f2bf(o);
  }
}

// ================= GEMM: C[M,N] = A[M,K](bf16) @ Bw[N,K](bf16)^T + bias =================
// m97 schedule: 128x128 tile, BK=32, double-buffered (32KB -> 4 blocks/CU),
// XOR-swizzled staging (0 bank conflicts), swapped-operand MFMA, vectorized epilogue.
// EPI 0: bf16 out; 2: bf16 out + gelu. TRV: sub==2 writes vT[b][h][d][s].
template<int EPI, bool TRV>
__global__ __launch_bounds__(256, 4)
void gemm_ker(const ushort* __restrict__ A,
              const ushort* __restrict__ B0, const ushort* __restrict__ B1,
              const ushort* __restrict__ B2,
              const float* __restrict__ bias0, const float* __restrict__ bias1,
              const float* __restrict__ bias2,
              void* __restrict__ C0, void* __restrict__ C1, void* __restrict__ C2,
              int Kdim, int nblk)
{
  __shared__ ushort As[2][128 * 32];
  __shared__ ushort Bs[2][128 * 32];

  int id = blockIdx.y * gridDim.x + blockIdx.x;
  const int chunk = (gridDim.x * gridDim.y) >> 3;
  id = (id & 7) * chunk + (id >> 3);
  const int bm = id & 63;
  const int bnAll = id >> 6;
  const int sub = bnAll / nblk;
  const int bn = bnAll - sub * nblk;

  const ushort* Bw  = sub == 0 ? B0 : (sub == 1 ? B1 : B2);
  const float* bias = sub == 0 ? bias0 : (sub == 1 ? bias1 : bias2);
  const int Ndim = nblk * 128;

  const int tid = threadIdx.x;
  const int l = tid & 63, w = tid >> 6;
  const int wm = w >> 1, wn = w & 1;
  const int fr = l & 15, fg = l >> 4;

  const int srow_in = l >> 2;
  const int gks = ((l & 3) ^ ((l >> 3) & 3)) * 8;
  const ushort* Agl0 = A  + (size_t)(bm * 128 + w * 16 + srow_in) * Kdim + gks;
  const ushort* Agl1 = Agl0 + (size_t)64 * Kdim;
  const ushort* Bgl0 = Bw + (size_t)(bn * 128 + w * 16 + srow_in) * Kdim + gks;
  const ushort* Bgl1 = Bgl0 + (size_t)64 * Kdim;

  auto stage = [&](int b, int kt) {
    const int ko = kt * 32;
    ushort* al = &As[b][w * 64 * 8];
    ushort* bl = &Bs[b][w * 64 * 8];
    glds16(Agl0 + ko, al);
    glds16(Agl1 + ko, al + 256 * 8);
    glds16(Bgl0 + ko, bl);
    glds16(Bgl1 + ko, bl + 256 * 8);
  };

  const int se = (fg ^ ((fr >> 1) & 3)) * 8;

  f32x4 acc[4][4];
#pragma unroll
  for (int i = 0; i < 4; ++i)
#pragma unroll
    for (int j = 0; j < 4; ++j) acc[i][j] = f32x4{0.f, 0.f, 0.f, 0.f};

  stage(0, 0);
  __syncthreads();

  const int nk = Kdim >> 5;
  int cur = 0;
  for (int kt = 0; kt < nk; ++kt) {
    if (kt + 1 < nk) stage(cur ^ 1, kt + 1);

    bf16x8 af[4], bfv[4];
#pragma unroll
    for (int i = 0; i < 4; ++i)
      af[i]  = *(const bf16x8*)&As[cur][(wm * 64 + i * 16 + fr) * 32 + se];
#pragma unroll
    for (int j = 0; j < 4; ++j)
      bfv[j] = *(const bf16x8*)&Bs[cur][(wn * 64 + j * 16 + fr) * 32 + se];

    __builtin_amdgcn_s_setprio(1);
#pragma unroll
    for (int i = 0; i < 4; ++i)
#pragma unroll
      for (int j = 0; j < 4; ++j)
        acc[i][j] = __builtin_amdgcn_mfma_f32_16x16x32_bf16(bfv[j], af[i], acc[i][j], 0, 0, 0);
    __builtin_amdgcn_s_setprio(0);

    __syncthreads();
    cur ^= 1;
  }

#pragma unroll
  for (int i = 0; i < 4; ++i) {
    const int row_g = bm * 128 + wm * 64 + i * 16 + fr;
#pragma unroll
    for (int j = 0; j < 4; ++j) {
      const int col = bn * 128 + wn * 64 + j * 16 + fg * 4;
      const float4 bv4 = *(const float4*)&bias[col];
      const float v0 = acc[i][j][0] + bv4.x;
      const float v1 = acc[i][j][1] + bv4.y;
      const float v2 = acc[i][j][2] + bv4.z;
      const float v3 = acc[i][j][3] + bv4.w;
      if (TRV && sub == 2) {
        const int b_ = row_g >> 9, s_ = row_g & 511;
        const int h_ = col >> 6, d0 = col & 63;
        ushort* vp = (ushort*)C2 + (((size_t)(b_ * HH + h_) * DHD + d0) * SS + s_);
        vp[0] = f2bf(v0); vp[SS] = f2bf(v1); vp[2 * SS] = f2bf(v2); vp[3 * SS] = f2bf(v3);
      } else if (EPI == 2) {
        ushort4 o4;
        o4.x = f2bf(gelu_t(v0)); o4.y = f2bf(gelu_t(v1));
        o4.z = f2bf(gelu_t(v2)); o4.w = f2bf(gelu_t(v3));
        *(ushort4*)&((ushort*)C0)[(size_t)row_g * Ndim + col] = o4;
      } else {
        void* Cout = sub == 0 ? C0 : (sub == 1 ? C1 : C2);
        ushort4 o4;
        o4.x = f2bf(v0); o4.y = f2bf(v1); o4.z = f2bf(v2); o4.w = f2bf(v3);
        *(ushort4*)&((ushort*)Cout)[(size_t)row_g * Ndim + col] = o4;
      }
    }
  }
}

// ================= split-K=2 GEMM for N=768 (O-proj, Wd) — bf16 partials =================
// grid (64, 12): y encodes bn (6) x sk (2). bf16 partials to P0/P1; bias in sk==0.
__global__ __launch_bounds__(256, 4)
void gemm_sk(const ushort* __restrict__ A, const ushort* __restrict__ Bw,
             const float* __restrict__ bias, ushort* __restrict__ P0,
             ushort* __restrict__ P1, int Kdim)
{
  __shared__ ushort As[2][128 * 32];
  __shared__ ushort Bs[2][128 * 32];

  int id = blockIdx.y * gridDim.x + blockIdx.x;
  const int chunk = (gridDim.x * gridDim.y) >> 3;
  id = (id & 7) * chunk + (id >> 3);
  const int bm = id & 63;
  const int rest = id >> 6;
  const int bn = rest >> 1;
  const int sk = rest & 1;

  const int Kh = Kdim >> 1;

  const int tid = threadIdx.x;
  const int l = tid & 63, w = tid >> 6;
  const int wm = w >> 1, wn = w & 1;
  const int fr = l & 15, fg = l >> 4;

  const int srow_in = l >> 2;
  const int gks = ((l & 3) ^ ((l >> 3) & 3)) * 8;
  const ushort* Agl0 = A  + (size_t)(bm * 128 + w * 16 + srow_in) * Kdim + sk * Kh + gks;
  const ushort* Agl1 = Agl0 + (size_t)64 * Kdim;
  const ushort* Bgl0 = Bw + (size_t)(bn * 128 + w * 16 + srow_in) * Kdim + sk * Kh + gks;
  const ushort* Bgl1 = Bgl0 + (size_t)64 * Kdim;

  auto stage = [&](int b, int kt) {
    const int ko = kt * 32;
    ushort* al = &As[b][w * 64 * 8];
    ushort* bl = &Bs[b][w * 64 * 8];
    glds16(Agl0 + ko, al);
    glds16(Agl1 + ko, al + 256 * 8);
    glds16(Bgl0 + ko, bl);
    glds16(Bgl1 + ko, bl + 256 * 8);
  };

  const int se = (fg ^ ((fr >> 1) & 3)) * 8;

  f32x4 acc[4][4];
#pragma unroll
  for (int i = 0; i < 4; ++i)
#pragma unroll
    for (int j = 0; j < 4; ++j) acc[i][j] = f32x4{0.f, 0.f, 0.f, 0.f};

  stage(0, 0);
  __syncthreads();

  const int nk = Kh >> 5;
  int cur = 0;
  for (int kt = 0; kt < nk; ++kt) {
    if (kt + 1 < nk) stage(cur ^ 1, kt + 1);

    bf16x8 af[4], bfv[4];
#pragma unroll
    for (int i = 0; i < 4; ++i)
      af[i]  = *(const bf16x8*)&As[cur][(wm * 64 + i * 16 + fr) * 32 + se];
#pragma unroll
    for (int j = 0; j < 4; ++j)
      bfv[j] = *(const bf16x8*)&Bs[cur][(wn * 64 + j * 16 + fr) * 32 + se];

    __builtin_amdgcn_s_setprio(1);
#pragma unroll
    for (int i = 0; i < 4; ++i)
#pragma unroll
      for (int j = 0; j < 4; ++j)
        acc[i][j] = __builtin_amdgcn_mfma_f32_16x16x32_bf16(bfv[j], af[i], acc[i][j], 0, 0, 0);
    __builtin_amdgcn_s_setprio(0);

    __syncthreads();
    cur ^= 1;
  }

  ushort* P = sk ? P1 : P0;
  const float bs = sk ? 0.f : 1.f;
#pragma unroll
  for (int i = 0; i < 4; ++i) {
    const int row_g = bm * 128 + wm * 64 + i * 16 + fr;
#pragma unroll
    for (int j = 0; j < 4; ++j) {
      const int col = bn * 128 + wn * 64 + j * 16 + fg * 4;
      const float4 bv4 = *(const float4*)&bias[col];
      ushort4 o4;
      o4.x = f2bf(acc[i][j][0] + bv4.x * bs);
      o4.y = f2bf(acc[i][j][1] + bv4.y * bs);
      o4.z = f2bf(acc[i][j][2] + bv4.z * bs);
      o4.w = f2bf(acc[i][j][3] + bv4.w * bs);
      *(ushort4*)&P[(size_t)row_g * DD + col] = o4;
    }
  }
}

// ================= fused flash attention (V pre-transposed, QBLK=128) =================
// 512 threads = 8 waves, each wave owns 16 q-rows. grid (S/128, B*H).
__global__ __launch_bounds__(512, 2)
void attn_kernel(const ushort* __restrict__ qb, const ushort* __restrict__ kb,
                 const ushort* __restrict__ vt, const float* __restrict__ relt,
                 const float* __restrict__ amask, ushort* __restrict__ ctxb)
{
  __shared__ ushort Kt[128][72];
  __shared__ ushort Vt[64][136];
  __shared__ ushort Pl[128][136];
  __shared__ float am_lds[512];
  __shared__ float rel_lds[1024];

  const int tid = threadIdx.x, lane = tid & 63, w = tid >> 6;

  // XCD-chunked swizzle: all 4 q-tiles of one (b,h) land on one XCD
  int lin = blockIdx.y * gridDim.x + blockIdx.x;        // 0..767
  lin = (lin & 7) * 96 + (lin >> 3);
  const int qt = lin & 3;
  const int bh = lin >> 2;
  const int b = bh / HH, h = bh - b * HH;
  const int fr = lane & 15, fg = lane >> 4;

  am_lds[tid] = (1.0f - amask[b * SS + tid]) * -10000.0f;
  {
    int d0 = tid - 512;                               // [-512, -1]
    d0 = max(-128, d0);
    rel_lds[tid] = relt[(d0 + 128) * HH + h];
    int d1 = tid;                                     // [0, 511]
    d1 = min(128, d1);
    rel_lds[tid + 512] = relt[(d1 + 128) * HH + h];
  }

  bf16x8 qf[2];
  {
    const int qrow = qt * 128 + w * 16 + fr;
    const ushort* p = qb + ((size_t)(b * SS + qrow) * DD) + h * DHD + fg * 8;
    qf[0] = *(const bf16x8*)p;
    qf[1] = *(const bf16x8*)(p + 32);
  }

  f32x4 o[4];
  float mrow[4], lrow[4];
#pragma unroll
  for (int r = 0; r < 4; ++r) { mrow[r] = -1e30f; lrow[r] = 0.f; }
#pragma unroll
  for (int d = 0; d < 4; ++d) o[d] = f32x4{0.f, 0.f, 0.f, 0.f};

  const int skr = tid >> 2;            // K staging row 0..127
  const int shd = (tid & 3) * 16;      // K staging d-quarter
  const int vrow = tid >> 3;           // V staging row (d) 0..63
  const int vcg  = (tid & 7) * 16;     // V staging col group
  const ushort* vgl = vt + ((size_t)bh * DHD + vrow) * SS + vcg;

  const int qg0 = qt * 128 + w * 16;   // wave's first q row

  for (int kt = 0; kt < 4; ++kt) {
    const size_t gbase = ((size_t)(b * SS + kt * 128 + skr) * DD) + h * DHD + shd;
    int4 kr0 = *(const int4*)(kb + gbase);
    int4 kr1 = *(const int4*)(kb + gbase + 8);
    const ushort* vp = vgl + kt * 128;
    int4 vr0 = *(const int4*)(vp);
    int4 vr1 = *(const int4*)(vp + 8);

    __syncthreads();
    *(int4*)&Kt[skr][shd]     = kr0;
    *(int4*)&Kt[skr][shd + 8] = kr1;
    *(int4*)&Vt[vrow][vcg]     = vr0;
    *(int4*)&Vt[vrow][vcg + 8] = vr1;
    __syncthreads();

    float sv[8][4];
    __builtin_amdgcn_s_setprio(1);
#pragma unroll
    for (int kc = 0; kc < 8; ++kc) {
      f32x4 s = f32x4{0.f, 0.f, 0.f, 0.f};
      bf16x8 kf0 = *(const bf16x8*)&Kt[kc * 16 + fr][fg * 8];
      bf16x8 kf1 = *(const bf16x8*)&Kt[kc * 16 + fr][32 + fg * 8];
      s = __builtin_amdgcn_mfma_f32_16x16x32_bf16(qf[0], kf0, s, 0, 0, 0);
      s = __builtin_amdgcn_mfma_f32_16x16x32_bf16(qf[1], kf1, s, 0, 0, 0);
      const int col = kt * 128 + kc * 16 + fr;
      const float am = am_lds[col];
      const int ridx = col - qg0 - fg * 4 + 512;
#pragma unroll
      for (int r = 0; r < 4; ++r)
        sv[kc][r] = s[r] * 0.125f + rel_lds[ridx - r] + am;
    }
    __builtin_amdgcn_s_setprio(0);

    float ef[4];
#pragma unroll
    for (int r = 0; r < 4; ++r) {
      float tmax = sv[0][r];
#pragma unroll
      for (int kc = 1; kc < 8; ++kc) tmax = fmaxf(tmax, sv[kc][r]);
#pragma unroll
      for (int off = 1; off < 16; off <<= 1) tmax = fmaxf(tmax, __shfl_xor(tmax, off));
      const float mnew = fmaxf(mrow[r], tmax);
      ef[r] = __expf(mrow[r] - mnew);
      float psum = 0.f;
      const int prow = w * 16 + fg * 4 + r;
#pragma unroll
      for (int kc = 0; kc < 8; ++kc) {
        float p = __expf(sv[kc][r] - mnew);
        psum += p;
        Pl[prow][kc * 16 + fr] = f2bf(p);
      }
#pragma unroll
      for (int off = 1; off < 16; off <<= 1) psum += __shfl_xor(psum, off);
      lrow[r] = lrow[r] * ef[r] + psum;
      mrow[r] = mnew;
    }
#pragma unroll
    for (int dc = 0; dc < 4; ++dc)
#pragma unroll
      for (int r = 0; r < 4; ++r) o[dc][r] *= ef[r];
    __syncthreads();

    __builtin_amdgcn_s_setprio(1);
#pragma unroll
    for (int dc = 0; dc < 4; ++dc)
#pragma unroll
      for (int ks = 0; ks < 4; ++ks) {
        bf16x8 pf = *(const bf16x8*)&Pl[w * 16 + fr][ks * 32 + fg * 8];
        bf16x8 vf = *(const bf16x8*)&Vt[dc * 16 + fr][ks * 32 + fg * 8];
        o[dc] = __builtin_amdgcn_mfma_f32_16x16x32_bf16(pf, vf, o[dc], 0, 0, 0);
      }
    __builtin_amdgcn_s_setprio(0);
  }

#pragma unroll
  for (int dc = 0; dc < 4; ++dc)
#pragma unroll
    for (int r = 0; r < 4; ++r) {
      const int qg = qt * 128 + w * 16 + fg * 4 + r;
      const float v = o[dc][r] / lrow[r];
      ctxb[((size_t)(b * SS + qg) * DD) + h * DHD + dc * 16 + fr] = f2bf(v);
    }
}

// ================= host launch =================
extern "C" void kernel_launch(void* const* d_in, const int* in_sizes, int n_in,
                              void* d_out, int out_size, void* d_ws, size_t ws_size,
                              hipStream_t stream) {
  const int*   ids   = (const int*)d_in[0];
  const float* amask = (const float*)d_in[1];
  const float* wemb  = (const float*)d_in[2];
  const float* pemb  = (const float*)d_in[3];
  const float* eln_w = (const float*)d_in[4];
  const float* eln_b = (const float*)d_in[5];
  const float* relt  = (const float*)d_in[6];
  const float* Wq    = (const float*)d_in[7];
  const float* bq    = (const float*)d_in[8];
  const float* Wk    = (const float*)d_in[9];
  const float* bk    = (const float*)d_in[10];
  const float* Wv    = (const float*)d_in[11];
  const float* bv    = (const float*)d_in[12];
  const float* Wo    = (const float*)d_in[13];
  const float* bo    = (const float*)d_in[14];
  const float* aln_w = (const float*)d_in[15];
  const float* aln_b = (const float*)d_in[16];
  const float* Wi    = (const float*)d_in[17];
  const float* bi    = (const float*)d_in[18];
  const float* Wd    = (const float*)d_in[19];
  const float* bd    = (const float*)d_in[20];
  const float* oln_w = (const float*)d_in[21];
  const float* oln_b = (const float*)d_in[22];

  size_t off = 0;
  auto carve = [&](size_t bytes) -> void* {
    void* r = (char*)d_ws + off;
    off += (bytes + 255) & ~(size_t)255;
    return r;
  };
  float*  hf     = (float*) carve((size_t)MM * DD * 4);
  ushort* hb     = (ushort*)carve((size_t)MM * DD * 2);
  ushort* qbuf   = (ushort*)carve((size_t)MM * DD * 2);
  ushort* kbuf   = (ushort*)carve((size_t)MM * DD * 2);
  ushort* vbuf   = (ushort*)carve((size_t)MM * DD * 2);   // vT[b][h][d][s]
  ushort* ctxb   = (ushort*)carve((size_t)MM * DD * 2);
  ushort* gout   = (ushort*)carve((size_t)MM * DD * 2);   // split-K partial 0 (bf16)
  ushort* gout2  = (ushort*)carve((size_t)MM * DD * 2);   // split-K partial 1 (bf16)
  ushort* interb = (ushort*)carve((size_t)MM * FF * 2);
  const int PD = DD * DD;
  const int PF = FF * DD;
  ushort* wBded  = (ushort*)carve((size_t)2 * PF * 2);    // Wi,Wd bf16 (dedicated)

  ushort* wA = interb;   // Wq,Wk,Wv,Wo bf16 in interb's dead window

  embed_ln_kernel<<<MM, 256, 0, stream>>>(ids, wemb, pemb, eln_w, eln_b, hf, hb);

  const dim3 gQKV(MM / 128, 3 * (DD / 128));  // 64 x 18
  const dim3 gSK(MM / 128, 2 * (DD / 128));   // 64 x 12 (split-K=2)
  const dim3 gF(MM / 128, FF / 128);          // 64 x 24
  const dim3 gA(SS / 128, BB * HH);           // 4 x 192
  const dim3 gC(PF / 1024, 6);                // 2304 x 6

  for (int l = 0; l < LL; ++l) {
    const size_t wo  = (size_t)l * PD;
    const size_t wio = (size_t)l * PF;

    convw6<<<gC, 256, 0, stream>>>(Wq + wo, Wk + wo, Wv + wo, Wo + wo,
                                   Wi + wio, Wd + wio, wA, wBded, PD, PF);

    gemm_ker<0, true><<<gQKV, 256, 0, stream>>>(hb, wA, wA + PD, wA + 2 * PD,
                                                bq + l * DD, bk + l * DD, bv + l * DD,
                                                qbuf, kbuf, vbuf, DD, DD / 128);

    attn_kernel<<<gA, 512, 0, stream>>>(qbuf, kbuf, vbuf, relt, amask, ctxb);

    gemm_sk<<<gSK, 256, 0, stream>>>(ctxb, wA + 3 * PD, bo + l * DD, gout, gout2, DD);
    add_ln2_kernel<<<MM, 256, 0, stream>>>(hf, gout, gout2,
                                           aln_w + l * DD, aln_b + l * DD, hf, hb);

    gemm_ker<2, false><<<gF, 256, 0, stream>>>(hb, wBded, wBded, wBded,
                                               bi + l * FF, bi + l * FF, bi + l * FF,
                                               interb, interb, interb, DD, FF / 128);
    gemm_sk<<<gSK, 256, 0, stream>>>(interb, wBded + PF, bd + l * DD, gout, gout2, FF);

    float* outp = (l == LL - 1) ? (float*)d_out : hf;
    add_ln2_kernel<<<MM, 256, 0, stream>>>(hf, gout, gout2,
                                           oln_w + l * DD, oln_b + l * DD, outp, hb);
  }
}